// Round 6
// baseline (10885.354 us; speedup 1.0000x reference)
//
#include <hip/hip_runtime.h>

// Seq2Seq round 10: launch->grid-barrier, bodies UNCHANGED from r4 (4592us).
//  - enc_persist3: 128 blocks, per-step body == enc_step2, 1 barrier/step.
//  - dec_persist3: 128 blocks, 6 phases/step == r4's six kernels verbatim
//    (u_c GEMM 16blk / attn1 128blk / u_p GEMM 16blk / attn2 / hk 16blk /
//    gates 64blk), 6 barriers/step. No GEMVs (r3/r5 lesson), all MFMA.
//  - Everything else (prep, projE hoist, env, logits): r4 verbatim.
// Dispatches: ~340 -> ~14.

typedef unsigned short u16;
typedef __attribute__((ext_vector_type(8))) short bf16x8;
typedef __attribute__((ext_vector_type(4))) float f32x4;

#define DEVFN static __device__ __forceinline__

DEVFN float bf2f(u16 u) {
  unsigned int x = ((unsigned int)u) << 16;
  float f; __builtin_memcpy(&f, &x, 4); return f;
}
DEVFN u16 f2bf(float f) {
  unsigned int x; __builtin_memcpy(&x, &f, 4);
  x = (x + 0x7fffu + ((x >> 16) & 1u)) >> 16;
  return (u16)x;
}
DEVFN float sigf(float x) { return 1.f / (1.f + __expf(-x)); }
DEVFN bf16x8 load8(const u16* p) { return *(const bf16x8*)p; }
DEVFN int clampi(int v, int lo, int hi) { return v < lo ? lo : (v > hi ? hi : v); }

// ---------------------------------------------------------------------------
// Device-scope grid barrier (sense-reversing; silicon-proven in r2/r3).
// ---------------------------------------------------------------------------
DEVFN void grid_bar(unsigned int* bar, int nblk) {
  __syncthreads();
  if (threadIdx.x == 0) {
    __threadfence();
    unsigned int g = __hip_atomic_load(bar + 1, __ATOMIC_RELAXED, __HIP_MEMORY_SCOPE_AGENT);
    unsigned int t = __hip_atomic_fetch_add(bar, 1u, __ATOMIC_ACQ_REL, __HIP_MEMORY_SCOPE_AGENT);
    if (t == (unsigned int)(nblk - 1)) {
      __hip_atomic_store(bar, 0u, __ATOMIC_RELAXED, __HIP_MEMORY_SCOPE_AGENT);
      __hip_atomic_fetch_add(bar + 1, 1u, __ATOMIC_RELEASE, __HIP_MEMORY_SCOPE_AGENT);
    } else {
      while (__hip_atomic_load(bar + 1, __ATOMIC_ACQUIRE, __HIP_MEMORY_SCOPE_AGENT) == g)
        __builtin_amdgcn_s_sleep(2);
    }
  }
  __syncthreads();
}

__global__ void bar_init(unsigned int* bar) {
  if (threadIdx.x < 64) bar[threadIdx.x] = 0;
}

// ---------------------------------------------------------------------------
// Generic MFMA GEMM kernel (prep/logits/projE only). EPI0: f32 out (+bias).
// ---------------------------------------------------------------------------
struct GemmArgs {
  const u16* A; int lda; int M;
  const u16* W; int ldw; int N; int K;
  void* out; int ldc;
  const float* bias;
};

__global__ __launch_bounds__(256) void gemm_k(GemmArgs g) {
  int lane = threadIdx.x & 63;
  int wave = threadIdx.x >> 6;
  int col = lane & 15, q = lane >> 4;
  int m0 = blockIdx.x * 64 + (wave >> 1) * 32;
  int n0 = blockIdx.y * 64 + (wave & 1) * 32;
  f32x4 acc[2][2] = {};
  int rA[2] = { m0 + col, m0 + 16 + col };
  int rB[2] = { n0 + col, n0 + 16 + col };
  bool gA[2] = { rA[0] < g.M, rA[1] < g.M };
  bool gB[2] = { rB[0] < g.N, rB[1] < g.N };
  const u16* pA[2]; const u16* pB[2];
#pragma unroll
  for (int i = 0; i < 2; i++) {
    pA[i] = g.A + (size_t)(gA[i] ? rA[i] : 0) * g.lda + q * 8;
    pB[i] = g.W + (size_t)(gB[i] ? rB[i] : 0) * g.ldw + q * 8;
  }
  bf16x8 zf = {0,0,0,0,0,0,0,0};
  for (int k = 0; k < g.K; k += 32) {
    bf16x8 a0 = gA[0] ? load8(pA[0] + k) : zf;
    bf16x8 a1 = gA[1] ? load8(pA[1] + k) : zf;
    bf16x8 b0 = gB[0] ? load8(pB[0] + k) : zf;
    bf16x8 b1 = gB[1] ? load8(pB[1] + k) : zf;
    acc[0][0] = __builtin_amdgcn_mfma_f32_16x16x32_bf16(a0, b0, acc[0][0], 0, 0, 0);
    acc[0][1] = __builtin_amdgcn_mfma_f32_16x16x32_bf16(a0, b1, acc[0][1], 0, 0, 0);
    acc[1][0] = __builtin_amdgcn_mfma_f32_16x16x32_bf16(a1, b0, acc[1][0], 0, 0, 0);
    acc[1][1] = __builtin_amdgcn_mfma_f32_16x16x32_bf16(a1, b1, acc[1][1], 0, 0, 0);
  }
#pragma unroll
  for (int mi = 0; mi < 2; mi++)
#pragma unroll
    for (int ni = 0; ni < 2; ni++)
#pragma unroll
      for (int r = 0; r < 4; r++) {
        int m = m0 + mi * 16 + q * 4 + r;
        int n = n0 + ni * 16 + col;
        if (m >= g.M || n >= g.N) continue;
        float v = acc[mi][ni][r];
        if (g.bias) v += g.bias[n];
        ((float*)g.out)[(size_t)m * g.ldc + n] = v;
      }
}

// ---------------------------------------------------------------------------
// Decoder phase bodies (r4 kernels verbatim, as device functions)
// ---------------------------------------------------------------------------
// u_c / u_p projection GEMM: M=128, N=512, exact tiles, f32 out, no bias.
DEVFN void gemm_nb_body(int bx, int by, const u16* A, int lda,
                        const u16* W, int ldw, int K, float* out, int ldc) {
  int lane = threadIdx.x & 63, wave = threadIdx.x >> 6;
  int col = lane & 15, q = lane >> 4;
  int m0 = bx * 64 + (wave >> 1) * 32;
  int n0 = by * 64 + (wave & 1) * 32;
  f32x4 acc[2][2] = {};
  const u16* pA[2]; const u16* pB[2];
#pragma unroll
  for (int i = 0; i < 2; i++) {
    pA[i] = A + (size_t)(m0 + i * 16 + col) * lda + q * 8;
    pB[i] = W + (size_t)(n0 + i * 16 + col) * ldw + q * 8;
  }
  for (int k = 0; k < K; k += 32) {
    bf16x8 a0 = load8(pA[0] + k);
    bf16x8 a1 = load8(pA[1] + k);
    bf16x8 b0 = load8(pB[0] + k);
    bf16x8 b1 = load8(pB[1] + k);
    acc[0][0] = __builtin_amdgcn_mfma_f32_16x16x32_bf16(a0, b0, acc[0][0], 0, 0, 0);
    acc[0][1] = __builtin_amdgcn_mfma_f32_16x16x32_bf16(a0, b1, acc[0][1], 0, 0, 0);
    acc[1][0] = __builtin_amdgcn_mfma_f32_16x16x32_bf16(a1, b0, acc[1][0], 0, 0, 0);
    acc[1][1] = __builtin_amdgcn_mfma_f32_16x16x32_bf16(a1, b1, acc[1][1], 0, 0, 0);
  }
#pragma unroll
  for (int mi = 0; mi < 2; mi++)
#pragma unroll
    for (int ni = 0; ni < 2; ni++)
#pragma unroll
      for (int r = 0; r < 4; r++) {
        int m = m0 + mi * 16 + q * 4 + r;
        int n = n0 + ni * 16 + col;
        out[(size_t)m * ldc + n] = acc[mi][ni][r];
      }
}

DEVFN void attn1_body(int b, const float* u_c, const u16* insenc,
                      u16* qattn, u16* qbuf, float* sh) {
  float* su = sh; float* red = sh + 512; float* aw = sh + 768;
  int tid = threadIdx.x;
  for (int d = tid; d < 512; d += 256) su[d] = u_c[b * 512 + d];
  __syncthreads();
  {
    int l = tid >> 2, part = tid & 3;
    const u16* row = insenc + ((size_t)b * 64 + l) * 512 + part * 128;
    float s = 0.f;
    for (int k = 0; k < 128; k += 8) {
      bf16x8 v = load8(row + k);
#pragma unroll
      for (int e = 0; e < 8; e++) s += bf2f((u16)v[e]) * su[part * 128 + k + e];
    }
    red[tid] = s;
  }
  __syncthreads();
  if (tid < 64) {
    float sc = red[tid * 4] + red[tid * 4 + 1] + red[tid * 4 + 2] + red[tid * 4 + 3];
    float m = sc;
    for (int off = 32; off > 0; off >>= 1) m = fmaxf(m, __shfl_xor(m, off));
    float e = __expf(sc - m);
    float sm = e;
    for (int off = 32; off > 0; off >>= 1) sm += __shfl_xor(sm, off);
    aw[tid] = e / sm;
  }
  __syncthreads();
  for (int d = tid; d < 512; d += 256) {
    float z = 0.f;
    for (int l = 0; l < 64; l++) z += aw[l] * bf2f(insenc[((size_t)b * 64 + l) * 512 + d]);
    u16 zb = f2bf(z);
    qattn[(size_t)b * 1024 + d] = zb;
    qbuf[(size_t)b * 1024 + 512 + d] = zb;
  }
}

DEVFN void attn2_body(int b, const float* u_p, const u16* hisenc,
                      u16* qattn, float* sh) {
  float* su = sh; float* red = sh + 512; float* aw = sh + 768; float* mr = sh + 896;
  int tid = threadIdx.x;
  for (int d = tid; d < 512; d += 256) su[d] = u_p[b * 512 + d];
  __syncthreads();
  {
    int l = tid >> 1, part = tid & 1;
    const u16* row = hisenc + ((size_t)b * 128 + l) * 512 + part * 256;
    float s = 0.f;
    for (int k = 0; k < 256; k += 8) {
      bf16x8 v = load8(row + k);
#pragma unroll
      for (int e = 0; e < 8; e++) s += bf2f((u16)v[e]) * su[part * 256 + k + e];
    }
    red[tid] = s;
  }
  __syncthreads();
  float sc = (tid < 128) ? red[tid * 2] + red[tid * 2 + 1] : 0.f;
  __syncthreads();
  if (tid < 128) red[tid] = sc;
  __syncthreads();
  if (tid < 64) {
    float m = fmaxf(red[tid], red[tid + 64]);
    for (int off = 32; off > 0; off >>= 1) m = fmaxf(m, __shfl_xor(m, off));
    if (tid == 0) mr[0] = m;
  }
  __syncthreads();
  float ex = 0.f;
  if (tid < 128) { ex = __expf(sc - mr[0]); red[tid] = ex; }
  __syncthreads();
  if (tid < 64) {
    float s2 = red[tid] + red[tid + 64];
    for (int off = 32; off > 0; off >>= 1) s2 += __shfl_xor(s2, off);
    if (tid == 0) mr[1] = s2;
  }
  __syncthreads();
  if (tid < 128) aw[tid] = ex / mr[1];
  __syncthreads();
  for (int d = tid; d < 512; d += 256) {
    float z = 0.f;
    for (int l = 0; l < 128; l++) z += aw[l] * bf2f(hisenc[((size_t)b * 128 + l) * 512 + d]);
    qattn[(size_t)b * 1024 + 512 + d] = f2bf(z);
  }
}

DEVFN void hk_body(int bx, int by, const u16* qattn, const u16* wbd01,
                   const float* hk_base, const float* proj_act,
                   const int* actions, int t, u16* zin_cur) {
  int lane = threadIdx.x & 63, wave = threadIdx.x >> 6;
  int col = lane & 15, q = lane >> 4;
  int m0 = bx * 64 + (wave >> 1) * 32;
  int n0 = by * 64 + (wave & 1) * 32;
  f32x4 acc[2][2] = {};
  const u16* pA[2]; const u16* pB[2];
#pragma unroll
  for (int i = 0; i < 2; i++) {
    pA[i] = qattn + (size_t)(m0 + i * 16 + col) * 1024 + q * 8;
    pB[i] = wbd01 + (size_t)(n0 + i * 16 + col) * 1024 + q * 8;
  }
  for (int k = 0; k < 1024; k += 32) {
    bf16x8 a0 = load8(pA[0] + k);
    bf16x8 a1 = load8(pA[1] + k);
    bf16x8 b0 = load8(pB[0] + k);
    bf16x8 b1 = load8(pB[1] + k);
    acc[0][0] = __builtin_amdgcn_mfma_f32_16x16x32_bf16(a0, b0, acc[0][0], 0, 0, 0);
    acc[0][1] = __builtin_amdgcn_mfma_f32_16x16x32_bf16(a0, b1, acc[0][1], 0, 0, 0);
    acc[1][0] = __builtin_amdgcn_mfma_f32_16x16x32_bf16(a1, b0, acc[1][0], 0, 0, 0);
    acc[1][1] = __builtin_amdgcn_mfma_f32_16x16x32_bf16(a1, b1, acc[1][1], 0, 0, 0);
  }
#pragma unroll
  for (int mi = 0; mi < 2; mi++)
#pragma unroll
    for (int ni = 0; ni < 2; ni++)
#pragma unroll
      for (int r = 0; r < 4; r++) {
        int m = m0 + mi * 16 + q * 4 + r;
        int n = n0 + ni * 16 + col;
        int act = clampi(actions[m * 32 + t], 0, 99);
        float v = acc[mi][ni][r] + hk_base[m * 512 + n] + proj_act[(size_t)act * 512 + n];
        zin_cur[(size_t)m * 1024 + n] = f2bf(tanhf(v));
      }
}

DEVFN void gates_body(int bx, int by,
                      const u16* zin_cur, const u16* Wih, const u16* Whh,
                      const float* bias_int, float* c_ws, u16* zin_nxt,
                      u16* qbuf, u16* outs, int t, float (*ls)[68]) {
  int lane = threadIdx.x & 63, wave = threadIdx.x >> 6;
  int col = lane & 15, q = lane >> 4;
  int m0 = bx * 64 + (wave >> 1) * 32;
  int n0 = by * 64 + (wave & 1) * 32;
  f32x4 acc[2][2] = {};
  const u16* pA[2]; const u16* pI[2]; const u16* pH[2];
#pragma unroll
  for (int i = 0; i < 2; i++) {
    pA[i] = zin_cur + (size_t)(m0 + i * 16 + col) * 1024 + q * 8;
    int r = n0 + i * 16 + col;
    int src = (r & 3) * 512 + (r >> 2);
    pI[i] = Wih + (size_t)src * 512 + q * 8;
    pH[i] = Whh + (size_t)src * 512 + q * 8;
  }
  for (int k = 0; k < 512; k += 32) {
    bf16x8 a0 = load8(pA[0] + k);
    bf16x8 a1 = load8(pA[1] + k);
    bf16x8 b0 = load8(pI[0] + k);
    bf16x8 b1 = load8(pI[1] + k);
    acc[0][0] = __builtin_amdgcn_mfma_f32_16x16x32_bf16(a0, b0, acc[0][0], 0, 0, 0);
    acc[0][1] = __builtin_amdgcn_mfma_f32_16x16x32_bf16(a0, b1, acc[0][1], 0, 0, 0);
    acc[1][0] = __builtin_amdgcn_mfma_f32_16x16x32_bf16(a1, b0, acc[1][0], 0, 0, 0);
    acc[1][1] = __builtin_amdgcn_mfma_f32_16x16x32_bf16(a1, b1, acc[1][1], 0, 0, 0);
  }
  for (int k = 0; k < 512; k += 32) {
    bf16x8 a0 = load8(pA[0] + 512 + k);
    bf16x8 a1 = load8(pA[1] + 512 + k);
    bf16x8 b0 = load8(pH[0] + k);
    bf16x8 b1 = load8(pH[1] + k);
    acc[0][0] = __builtin_amdgcn_mfma_f32_16x16x32_bf16(a0, b0, acc[0][0], 0, 0, 0);
    acc[0][1] = __builtin_amdgcn_mfma_f32_16x16x32_bf16(a0, b1, acc[0][1], 0, 0, 0);
    acc[1][0] = __builtin_amdgcn_mfma_f32_16x16x32_bf16(a1, b0, acc[1][0], 0, 0, 0);
    acc[1][1] = __builtin_amdgcn_mfma_f32_16x16x32_bf16(a1, b1, acc[1][1], 0, 0, 0);
  }
#pragma unroll
  for (int mi = 0; mi < 2; mi++)
#pragma unroll
    for (int ni = 0; ni < 2; ni++)
#pragma unroll
      for (int r = 0; r < 4; r++) {
        int nl = (wave & 1) * 32 + ni * 16 + col;
        int ml = (wave >> 1) * 32 + mi * 16 + q * 4 + r;
        ls[ml][nl] = acc[mi][ni][r] + bias_int[by * 64 + nl];
      }
  __syncthreads();
  int m = threadIdx.x & 63, grp = threadIdx.x >> 6;
  int gm = bx * 64 + m;
  int j0 = by * 16;
#pragma unroll
  for (int jl = 0; jl < 4; jl++) {
    int jc = grp * 4 + jl;
    float gi = ls[m][jc * 4 + 0];
    float gf = ls[m][jc * 4 + 1];
    float gg = ls[m][jc * 4 + 2];
    float go = ls[m][jc * 4 + 3];
    int j = j0 + jc;
    float cn = sigf(gf) * c_ws[gm * 512 + j] + sigf(gi) * tanhf(gg);
    c_ws[gm * 512 + j] = cn;
    float hn = sigf(go) * tanhf(cn);
    u16 hb = f2bf(hn);
    zin_nxt[(size_t)gm * 1024 + 512 + j] = hb;
    qbuf[(size_t)gm * 1024 + j] = hb;
    outs[((size_t)gm * 32 + t) * 512 + j] = hb;
  }
}

// ---------------------------------------------------------------------------
// PERSISTENT decoder: 128 blocks x 256 threads; 6 barriers/step; phase
// bodies identical to the r4 launch kernels.
// ---------------------------------------------------------------------------
__global__ __launch_bounds__(256) void dec_persist3(
    const float* h0, const float* c0,
    const u16* insenc, const u16* hisenc,
    const u16* wc, const u16* wp, const u16* wbd01,
    const float* hkbase, const float* projact, const int* actions,
    const u16* dwih, const u16* dwhh, const float* bdec,
    float* u_c, float* u_p,
    u16* qbuf, u16* qattn, u16* zin, float* c_dec, u16* outs,
    unsigned int* bar) {
  __shared__ float sh[64 * 68];
  int blk = blockIdx.x, tid = threadIdx.x;
  // init (dec_init body, strided over the grid)
  for (int idx = blk * 256 + tid; idx < 128 * 512; idx += 128 * 256) {
    int b = idx >> 9, d = idx & 511;
    u16 hv = f2bf(h0[idx]);
    zin[(size_t)b * 1024 + 512 + d] = hv;
    qbuf[(size_t)b * 1024 + d] = hv;
    c_dec[idx] = c0[idx];
  }
  grid_bar(bar, 128);
  for (int t = 0; t < 32; t++) {
    u16* zin_cur = zin + (size_t)(t & 1) * 128 * 1024;
    u16* zin_nxt = zin + (size_t)((t + 1) & 1) * 128 * 1024;
    if (blk < 16) gemm_nb_body(blk & 1, blk >> 1, qbuf, 1024, wc, 512, 512, u_c, 512);
    grid_bar(bar, 128);
    attn1_body(blk, u_c, insenc, qattn, qbuf, sh);
    grid_bar(bar, 128);
    if (blk < 16) gemm_nb_body(blk & 1, blk >> 1, qbuf, 1024, wp, 1024, 1024, u_p, 512);
    grid_bar(bar, 128);
    attn2_body(blk, u_p, hisenc, qattn, sh);
    grid_bar(bar, 128);
    if (blk < 16) hk_body(blk & 1, blk >> 1, qattn, wbd01, hkbase, projact, actions, t, zin_cur);
    grid_bar(bar, 128);
    if (blk < 64) gates_body(blk & 1, blk >> 1, zin_cur, dwih, dwhh, bdec,
                             c_dec, zin_nxt, qbuf, outs, t, (float(*)[68])sh);
    grid_bar(bar, 128);
  }
}

// ---------------------------------------------------------------------------
// PERSISTENT encoder: 128 blocks x 256 threads; per-step body == enc_step2;
// 1 barrier/step (h double-buffer exchange across the 4 jq-blocks per rowgroup).
// ---------------------------------------------------------------------------
#define HBUF ((size_t)4 * 128 * 256)
__global__ __launch_bounds__(256) void enc_persist3(
    const int* ins_tok, const int* his_tok,
    const float* projE_f, const float* projE_b,
    const u16* whh_f, const u16* whh_b,
    const float* bias_f, const float* bias_b,
    u16* h_enc, float* c_enc, u16* ins_enc, u16* his_enc,
    unsigned int* bar) {
  int chain = blockIdx.x >> 5;   // 0 ins_f, 1 ins_b, 2 his_f, 3 his_b
  int sub = blockIdx.x & 31;
  int sgrp = sub >> 2, jq = sub & 3;
  int w = threadIdx.x >> 6, lane = threadIdx.x & 63;
  int col = lane & 15, q = lane >> 4;
  int dir = chain & 1, his = chain >> 1;
  int L = his ? 128 : 64;
  const int* toks = his ? his_tok : ins_tok;
  const float* projE = dir ? projE_b : projE_f;
  const u16* whh = dir ? whh_b : whh_f;
  const float* bias = dir ? bias_b : bias_f;
  float* c_g = c_enc + (size_t)chain * 128 * 256;
  u16* out = his ? his_enc : ins_enc;

  int jw = jq * 64 + w * 16;
  int j = jw + col;
  const u16* wrow[4];
#pragma unroll
  for (int G = 0; G < 4; G++) wrow[G] = whh + (size_t)(G * 256 + jw + col) * 256 + q * 8;
  float bi = bias[j], bf = bias[256 + j], bg = bias[512 + j], bo = bias[768 + j];

  for (int t = 0; t < 128; t++) {
    if (t < L) {
      int t_x = dir ? (L - 1 - t) : t;
      const u16* h_rd = h_enc + ((size_t)((t & 1) ^ 1)) * HBUF + (size_t)chain * 128 * 256;
      u16* h_wr = h_enc + ((size_t)(t & 1)) * HBUF + (size_t)chain * 128 * 256;
      f32x4 acc[4] = {};
      if (t > 0) {
        const u16* hrow = h_rd + (size_t)(sgrp * 16 + col) * 256 + q * 8;
        for (int k = 0; k < 256; k += 32) {
          bf16x8 a = load8(hrow + k);
#pragma unroll
          for (int G = 0; G < 4; G++) {
            bf16x8 bb = load8(wrow[G] + k);
            acc[G] = __builtin_amdgcn_mfma_f32_16x16x32_bf16(a, bb, acc[G], 0, 0, 0);
          }
        }
      }
#pragma unroll
      for (int r = 0; r < 4; r++) {
        int s = q * 4 + r;
        int b = sgrp * 16 + s;
        int tok = clampi(toks[b * L + t_x], 0, 1999);
        const float* px = projE + (size_t)tok * 1024;
        float pi = acc[0][r] + px[j] + bi;
        float pf = acc[1][r] + px[256 + j] + bf;
        float pg = acc[2][r] + px[512 + j] + bg;
        float po = acc[3][r] + px[768 + j] + bo;
        float cold = (t > 0) ? c_g[b * 256 + j] : 0.f;
        float cn = sigf(pf) * cold + sigf(pi) * tanhf(pg);
        float hn = sigf(po) * tanhf(cn);
        c_g[b * 256 + j] = cn;
        u16 hb = f2bf(hn);
        h_wr[b * 256 + j] = hb;
        out[((size_t)b * L + t_x) * 512 + dir * 256 + j] = hb;
      }
    }
    grid_bar(bar, 128);
  }
}

// ---------------------------------------------------------------------------
// prep kernels (r4 verbatim)
// ---------------------------------------------------------------------------
struct CvtJob { const float* src; u16* dst; int R; int C; int ld; int c0; int tr; int blk0; };
struct CvtJobs { CvtJob j[15]; int njobs; };

__global__ void cvt_all(CvtJobs a) {
  int bid = blockIdx.x;
  int ji = 0;
  while (ji + 1 < a.njobs && bid >= a.j[ji + 1].blk0) ji++;
  CvtJob jb = a.j[ji];
  int idx = (bid - jb.blk0) * 256 + threadIdx.x;
  int n = jb.R * jb.C;
  if (idx >= n) return;
  int r = idx / jb.C, c = idx - r * jb.C;
  float v = jb.src[(size_t)r * jb.ld + jb.c0 + c];
  if (jb.tr) jb.dst[(size_t)c * jb.R + r] = f2bf(v);
  else jb.dst[idx] = f2bf(v);
}

__global__ void addcvt(const float* a, const float* b, float* o, int n) {
  int i = blockIdx.x * 256 + threadIdx.x;
  if (i < n) o[i] = a[i] + (b ? b[i] : 0.f);
}

__global__ void bdecint_build(const float* bih, const float* bhh, float* o) {
  int r = blockIdx.x * 256 + threadIdx.x; // 2048
  int j = r >> 2, gg = r & 3;
  o[r] = bih[gg * 512 + j] + bhh[gg * 512 + j];
}

__global__ void wsum_build(const float* Wbd, u16* Wsum) {
  int idx = blockIdx.x * 256 + threadIdx.x; // 512*896
  int n = idx / 896, j = idx % 896;
  int c1 = (j < 448) ? (1024 + j) : (1920 + (j - 448));
  int c2 = c1 + 448;
  Wsum[idx] = f2bf(Wbd[(size_t)n * 2944 + c1] + Wbd[(size_t)n * 2944 + c2]);
}

// ---------------------------------------------------------------------------
// Env encoder (r4 verbatim)
// ---------------------------------------------------------------------------
__global__ __launch_bounds__(256) void env_encode(
    const int* cur_env, const int* ini_env,
    const float* color_emb, const float* pos_emb,
    const float* wih, const float* whh, const float* bih, const float* bhh,
    u16* ctx_cat) {
  __shared__ float s_wih[128 * 33], s_whh[128 * 33], s_b[128], s_col[7 * 32];
  __shared__ float h_lds[8][33];
  int tid = threadIdx.x;
  for (int i = tid; i < 128 * 32; i += 256) {
    int r = i >> 5, k2 = i & 31;
    s_wih[r * 33 + k2] = wih[i];
    s_whh[r * 33 + k2] = whh[i];
  }
  for (int i = tid; i < 128; i += 256) s_b[i] = bih[i] + bhh[i];
  for (int i = tid; i < 224; i += 256) s_col[i] = color_emb[i];
  int sl = tid >> 5, j = tid & 31;
  int gseq = blockIdx.x * 8 + sl;
  int e = gseq / 896, rem = gseq % 896;
  int b = rem / 7, p = rem % 7;
  const int* env = e ? ini_env : cur_env;
  int eoff = e ? 0 : 448;
  h_lds[sl][j] = 0.f;
  __syncthreads();
  float cj = 0.f, hj = 0.f;
  for (int st = 0; st < 4; st++) {
    int tok = clampi(env[b * 35 + p * 5 + 1 + st], 0, 6);
    const float* x = &s_col[tok * 32];
    float pi = s_b[j], pf = s_b[32 + j], pg = s_b[64 + j], po = s_b[96 + j];
    for (int k = 0; k < 32; k++) {
      float xk = x[k], hk = h_lds[sl][k];
      pi += s_wih[j * 33 + k] * xk + s_whh[j * 33 + k] * hk;
      pf += s_wih[(32 + j) * 33 + k] * xk + s_whh[(32 + j) * 33 + k] * hk;
      pg += s_wih[(64 + j) * 33 + k] * xk + s_whh[(64 + j) * 33 + k] * hk;
      po += s_wih[(96 + j) * 33 + k] * xk + s_whh[(96 + j) * 33 + k] * hk;
    }
    cj = sigf(pf) * cj + sigf(pi) * tanhf(pg);
    hj = sigf(po) * tanhf(cj);
    __syncthreads();
    h_lds[sl][j] = hj;
    __syncthreads();
  }
  size_t base = (size_t)b * 896 + eoff + p * 64;
  ctx_cat[base + j] = f2bf(pos_emb[p * 32 + j]);
  ctx_cat[base + 32 + j] = f2bf(hj);
}

// ---------------------------------------------------------------------------
extern "C" void kernel_launch(void* const* d_in, const int* in_sizes, int n_in,
                              void* d_out, int out_size, void* d_ws, size_t ws_size,
                              hipStream_t stream) {
  const int* ins_tok = (const int*)d_in[0];
  const int* his_tok = (const int*)d_in[1];
  const int* actions = (const int*)d_in[2];
  const int* cur_env = (const int*)d_in[3];
  const int* ini_env = (const int*)d_in[4];
  const float* enc_emb = (const float*)d_in[5];
  const float* Wih_f = (const float*)d_in[6];
  const float* Whh_f = (const float*)d_in[7];
  const float* bih_f = (const float*)d_in[8];
  const float* bhh_f = (const float*)d_in[9];
  const float* Wih_b = (const float*)d_in[10];
  const float* Whh_b = (const float*)d_in[11];
  const float* bih_b = (const float*)d_in[12];
  const float* bhh_b = (const float*)d_in[13];
  const float* color_emb = (const float*)d_in[14];
  const float* pos_emb = (const float*)d_in[15];
  const float* ws_Wih = (const float*)d_in[16];
  const float* ws_Whh = (const float*)d_in[17];
  const float* ws_bih = (const float*)d_in[18];
  const float* ws_bhh = (const float*)d_in[19];
  const float* act_emb = (const float*)d_in[20];
  const float* W_c = (const float*)d_in[21];
  const float* W_p = (const float*)d_in[22];
  // d_in[23..26] are mathematically dead (uniform softmax over broadcast rows).
  const float* Wbd_W = (const float*)d_in[27];
  const float* Wbd_b = (const float*)d_in[28];
  const float* dec_Wih = (const float*)d_in[29];
  const float* dec_Whh = (const float*)d_in[30];
  const float* dec_bih = (const float*)d_in[31];
  const float* dec_bhh = (const float*)d_in[32];
  const float* h2a_W = (const float*)d_in[33];
  const float* h2a_b = (const float*)d_in[34];
  const float* h0 = (const float*)d_in[35];
  const float* c0 = (const float*)d_in[36];
  (void)in_sizes; (void)n_in; (void)out_size; (void)ws_size;

  char* ws = (char*)d_ws;
  size_t off = 0;
  auto alloc = [&](size_t bytes) -> char* {
    char* p = ws + off;
    off = (off + bytes + 255) & ~(size_t)255;
    return p;
  };
  u16* insenc   = (u16*)alloc(8192ull * 512 * 2);
  u16* hisenc   = (u16*)alloc(16384ull * 512 * 2);
  u16* outs     = (u16*)alloc(4096ull * 512 * 2);
  u16* Wsum     = (u16*)alloc(512ull * 896 * 2);
  u16* h_enc    = (u16*)alloc(2 * HBUF * 2);
  float* c_enc  = (float*)alloc(4ull * 128 * 256 * 4);
  float* projact= (float*)alloc(100ull * 512 * 4);
  float* bias_f = (float*)alloc(1024 * 4);
  float* bias_b = (float*)alloc(1024 * 4);
  float* bdecint= (float*)alloc(2048 * 4);
  float* bwbd   = (float*)alloc(512 * 4);
  float* bh2a   = (float*)alloc(128 * 4);
  u16* ctxcat   = (u16*)alloc(128ull * 896 * 2);
  float* hkbase = (float*)alloc(128ull * 512 * 4);
  float* u_c    = (float*)alloc(128ull * 512 * 4);
  float* u_p    = (float*)alloc(128ull * 512 * 4);
  u16* qbuf     = (u16*)alloc(128ull * 1024 * 2);     // [h | z_c]
  u16* qattn    = (u16*)alloc(128ull * 1024 * 2);     // [z_c | z_p]
  u16* zin      = (u16*)alloc(2ull * 128 * 1024 * 2); // [hk | h], parity
  float* c_dec  = (float*)alloc(128ull * 512 * 4);
  unsigned int* bar = (unsigned int*)alloc(256);
  // x-projection tables: projE = enc_emb @ Wih^T per direction (f32)
  float* projE_f = (float*)alloc(2000ull * 1024 * 4); // 8.2 MB
  float* projE_b = (float*)alloc(2000ull * 1024 * 4); // 8.2 MB
  // bf16 weight copies
  u16* emb_bf   = (u16*)alloc(2000ull * 128 * 2);
  u16* wihf_bf  = (u16*)alloc(1024ull * 128 * 2);
  u16* wihb_bf  = (u16*)alloc(1024ull * 128 * 2);
  u16* whhf_bf  = (u16*)alloc(1024ull * 256 * 2);
  u16* whhb_bf  = (u16*)alloc(1024ull * 256 * 2);
  u16* act_bf   = (u16*)alloc(100ull * 128 * 2);
  u16* wc_bf    = (u16*)alloc(512ull * 512 * 2);
  u16* wp_bf    = (u16*)alloc(512ull * 1024 * 2);
  u16* wbd01_bf = (u16*)alloc(512ull * 1024 * 2);
  u16* wbdx_bf  = (u16*)alloc(512ull * 128 * 2);
  u16* dwih_bf  = (u16*)alloc(2048ull * 512 * 2);
  u16* dwhh_bf  = (u16*)alloc(2048ull * 512 * 2);
  u16* h2a_bf   = (u16*)alloc(100ull * 512 * 2);

  // --- all weight conversions in ONE launch ---
  CvtJobs cj{};
  int nb = 0, jn = 0;
  auto addjob = [&](const float* s, u16* d, int R, int C, int ld, int c0c, int tr) {
    cj.j[jn] = { s, d, R, C, ld, c0c, tr, nb };
    nb += (R * C + 255) / 256;
    jn++;
  };
  addjob(enc_emb, emb_bf, 2000, 128, 128, 0, 0);
  addjob(Wih_f, wihf_bf, 1024, 128, 128, 0, 0);
  addjob(Wih_b, wihb_bf, 1024, 128, 128, 0, 0);
  addjob(Whh_f, whhf_bf, 1024, 256, 256, 0, 0);
  addjob(Whh_b, whhb_bf, 1024, 256, 256, 0, 0);
  addjob(act_emb, act_bf, 100, 128, 128, 0, 0);
  addjob(W_c, wc_bf, 512, 512, 512, 0, 0);
  addjob(W_p, wp_bf, 512, 1024, 1024, 0, 0);
  addjob(Wbd_W, wbd01_bf, 512, 1024, 2944, 0, 0);
  addjob(Wbd_W, wbdx_bf, 512, 128, 2944, 2816, 0);
  addjob(dec_Wih, dwih_bf, 2048, 512, 512, 0, 0);
  addjob(dec_Whh, dwhh_bf, 2048, 512, 512, 0, 0);
  addjob(h2a_W, h2a_bf, 100, 512, 512, 0, 0);
  cj.njobs = jn;
  cvt_all<<<nb, 256, 0, stream>>>(cj);

  // --- bias prep + barrier init ---
  addcvt<<<4, 256, 0, stream>>>(bih_f, bhh_f, bias_f, 1024);
  addcvt<<<4, 256, 0, stream>>>(bih_b, bhh_b, bias_b, 1024);
  addcvt<<<2, 256, 0, stream>>>(Wbd_b, nullptr, bwbd, 512);
  addcvt<<<1, 256, 0, stream>>>(h2a_b, nullptr, bh2a, 100);
  bdecint_build<<<8, 256, 0, stream>>>(dec_bih, dec_bhh, bdecint);
  wsum_build<<<1792, 256, 0, stream>>>(Wbd_W, Wsum);
  bar_init<<<1, 64, 0, stream>>>(bar);

  // --- projE tables: emb @ Wih^T per direction (M=2000, N=1024, K=128) ---
  {
    GemmArgs ge = {};
    ge.A = emb_bf; ge.lda = 128; ge.M = 2000; ge.W = wihf_bf; ge.ldw = 128;
    ge.N = 1024; ge.K = 128; ge.out = projE_f; ge.ldc = 1024;
    gemm_k<<<dim3(32, 16), 256, 0, stream>>>(ge);
    ge.W = wihb_bf; ge.out = projE_b;
    gemm_k<<<dim3(32, 16), 256, 0, stream>>>(ge);
  }

  // --- proj_act = act_emb @ Wbd_x^T + Wbd_b ---
  GemmArgs gp = {};
  gp.A = act_bf; gp.lda = 128; gp.M = 100; gp.W = wbdx_bf; gp.ldw = 128;
  gp.N = 512; gp.K = 128; gp.out = projact; gp.ldc = 512; gp.bias = bwbd;
  gemm_k<<<dim3(2, 8), 256, 0, stream>>>(gp);

  // --- env encode + hk_base ---
  env_encode<<<224, 256, 0, stream>>>(cur_env, ini_env, color_emb, pos_emb,
                                      ws_Wih, ws_Whh, ws_bih, ws_bhh, ctxcat);
  GemmArgs gb = {};
  gb.A = ctxcat; gb.lda = 896; gb.M = 128; gb.W = Wsum; gb.ldw = 896;
  gb.N = 512; gb.K = 896; gb.out = hkbase; gb.ldc = 512;
  gemm_k<<<dim3(2, 8), 256, 0, stream>>>(gb);

  // --- encoder: ONE persistent launch, bodies == enc_step2, 128 barriers ---
  enc_persist3<<<128, 256, 0, stream>>>(ins_tok, his_tok, projE_f, projE_b,
                                        whhf_bf, whhb_bf, bias_f, bias_b,
                                        h_enc, c_enc, insenc, hisenc, bar);

  // --- decoder: ONE persistent launch, bodies == r4 kernels, 193 barriers ---
  dec_persist3<<<128, 256, 0, stream>>>(h0, c0, insenc, hisenc,
                                        wc_bf, wp_bf, wbd01_bf,
                                        hkbase, projact, actions,
                                        dwih_bf, dwhh_bf, bdecint,
                                        u_c, u_p, qbuf, qattn, zin, c_dec, outs,
                                        bar + 32);

  // --- logits (f32 out) ---
  GemmArgs gl = {};
  gl.A = outs; gl.lda = 512; gl.M = 4096; gl.W = h2a_bf; gl.ldw = 512;
  gl.N = 100; gl.K = 512; gl.out = d_out; gl.ldc = 100; gl.bias = bh2a;
  gemm_k<<<dim3(64, 2), 256, 0, stream>>>(gl);
}

// Round 7
// 3894.242 us; speedup vs baseline: 2.7952x; 2.7952x over previous
//
#include <hip/hip_runtime.h>

// Seq2Seq round 11 = r4 (4592us, best) + 32x32-tile retile of the small
// decoder GEMMs (u_c/u_p/hk: 16 -> 64 blocks; logits: 128 -> 512 blocks).
// Mechanism: these GEMMs are latency-bound at 6% machine occupancy; smaller
// tiles = 4x the CUs issuing weight loads. No structural change.
// r6 lesson recorded: persistent kernels lose because agent-scope barrier
// fences flush per-XCD L2 -> 16MB/step refetch (FETCH 515MB). Launch-based
// structure is the right one for this workload.

typedef unsigned short u16;
typedef __attribute__((ext_vector_type(8))) short bf16x8;
typedef __attribute__((ext_vector_type(4))) float f32x4;

#define DEVFN static __device__ __forceinline__

DEVFN float bf2f(u16 u) {
  unsigned int x = ((unsigned int)u) << 16;
  float f; __builtin_memcpy(&f, &x, 4); return f;
}
DEVFN u16 f2bf(float f) {
  unsigned int x; __builtin_memcpy(&x, &f, 4);
  x = (x + 0x7fffu + ((x >> 16) & 1u)) >> 16;
  return (u16)x;
}
DEVFN float sigf(float x) { return 1.f / (1.f + __expf(-x)); }
DEVFN bf16x8 load8(const u16* p) { return *(const bf16x8*)p; }
DEVFN int clampi(int v, int lo, int hi) { return v < lo ? lo : (v > hi ? hi : v); }

// ---------------------------------------------------------------------------
// Generic MFMA GEMM (64x64 block tile): out[m,n] = sum_k A[m,k]*W[n,k].
// EPI 0: f32 out (+bias). EPI 2: hk epilogue.
// ---------------------------------------------------------------------------
struct GemmArgs {
  const u16* A; int lda; int M;
  const u16* W; int ldw; int N; int K;
  void* out; int ldc;
  const float* bias;
  const float* hk_base; const float* proj_act; const int* actions; int t;
};

template <int EPI>
__global__ __launch_bounds__(256) void gemm_k(GemmArgs g) {
  int lane = threadIdx.x & 63;
  int wave = threadIdx.x >> 6;
  int col = lane & 15, q = lane >> 4;
  int m0 = blockIdx.x * 64 + (wave >> 1) * 32;
  int n0 = blockIdx.y * 64 + (wave & 1) * 32;
  f32x4 acc[2][2] = {};
  int rA[2] = { m0 + col, m0 + 16 + col };
  int rB[2] = { n0 + col, n0 + 16 + col };
  bool gA[2] = { rA[0] < g.M, rA[1] < g.M };
  bool gB[2] = { rB[0] < g.N, rB[1] < g.N };
  const u16* pA[2]; const u16* pB[2];
#pragma unroll
  for (int i = 0; i < 2; i++) {
    pA[i] = g.A + (size_t)(gA[i] ? rA[i] : 0) * g.lda + q * 8;
    pB[i] = g.W + (size_t)(gB[i] ? rB[i] : 0) * g.ldw + q * 8;
  }
  bf16x8 zf = {0,0,0,0,0,0,0,0};
  for (int k = 0; k < g.K; k += 32) {
    bf16x8 a0 = gA[0] ? load8(pA[0] + k) : zf;
    bf16x8 a1 = gA[1] ? load8(pA[1] + k) : zf;
    bf16x8 b0 = gB[0] ? load8(pB[0] + k) : zf;
    bf16x8 b1 = gB[1] ? load8(pB[1] + k) : zf;
    acc[0][0] = __builtin_amdgcn_mfma_f32_16x16x32_bf16(a0, b0, acc[0][0], 0, 0, 0);
    acc[0][1] = __builtin_amdgcn_mfma_f32_16x16x32_bf16(a0, b1, acc[0][1], 0, 0, 0);
    acc[1][0] = __builtin_amdgcn_mfma_f32_16x16x32_bf16(a1, b0, acc[1][0], 0, 0, 0);
    acc[1][1] = __builtin_amdgcn_mfma_f32_16x16x32_bf16(a1, b1, acc[1][1], 0, 0, 0);
  }
#pragma unroll
  for (int mi = 0; mi < 2; mi++)
#pragma unroll
    for (int ni = 0; ni < 2; ni++)
#pragma unroll
      for (int r = 0; r < 4; r++) {
        int m = m0 + mi * 16 + q * 4 + r;
        int n = n0 + ni * 16 + col;
        if (m >= g.M || n >= g.N) continue;
        float v = acc[mi][ni][r];
        if constexpr (EPI == 0) {
          if (g.bias) v += g.bias[n];
          ((float*)g.out)[(size_t)m * g.ldc + n] = v;
        } else {
          int act = clampi(g.actions[m * 32 + g.t], 0, 99);
          v += g.hk_base[m * 512 + n] + g.proj_act[(size_t)act * 512 + n];
          ((u16*)g.out)[(size_t)m * g.ldc + n] = f2bf(tanhf(v));
        }
      }
}

// ---------------------------------------------------------------------------
// 32x32-block-tile MFMA GEMM: 4x the blocks of gemm_k -> 4x CUs issuing
// loads. For the small latency-bound decoder GEMMs (M=128) and logits.
// Wave w: rows m0+(w>>1)*16, cols n0+(w&1)*16; one f32x4 accumulator.
// ---------------------------------------------------------------------------
template <int EPI>
__global__ __launch_bounds__(256) void gemm32_k(GemmArgs g) {
  int lane = threadIdx.x & 63;
  int wave = threadIdx.x >> 6;
  int col = lane & 15, q = lane >> 4;
  int m0 = blockIdx.x * 32 + (wave >> 1) * 16;
  int n0 = blockIdx.y * 32 + (wave & 1) * 16;
  f32x4 acc = {};
  int rA = m0 + col, rB = n0 + col;
  bool gA = rA < g.M, gB = rB < g.N;
  const u16* pA = g.A + (size_t)(gA ? rA : 0) * g.lda + q * 8;
  const u16* pB = g.W + (size_t)(gB ? rB : 0) * g.ldw + q * 8;
  bf16x8 zf = {0,0,0,0,0,0,0,0};
  for (int k = 0; k < g.K; k += 32) {
    bf16x8 a = gA ? load8(pA + k) : zf;
    bf16x8 b = gB ? load8(pB + k) : zf;
    acc = __builtin_amdgcn_mfma_f32_16x16x32_bf16(a, b, acc, 0, 0, 0);
  }
#pragma unroll
  for (int r = 0; r < 4; r++) {
    int m = m0 + q * 4 + r;
    int n = n0 + col;
    if (m >= g.M || n >= g.N) continue;
    float v = acc[r];
    if constexpr (EPI == 0) {
      if (g.bias) v += g.bias[n];
      ((float*)g.out)[(size_t)m * g.ldc + n] = v;
    } else {
      int act = clampi(g.actions[m * 32 + g.t], 0, 99);
      v += g.hk_base[m * 512 + n] + g.proj_act[(size_t)act * 512 + n];
      ((u16*)g.out)[(size_t)m * g.ldc + n] = f2bf(tanhf(v));
    }
  }
}

// ---------------------------------------------------------------------------
// Decoder gates GEMM + fused LSTM cell (r0 verbatim). Gate rows r=(j*4+g).
// ---------------------------------------------------------------------------
__global__ __launch_bounds__(256) void dec_gates_cell(
    const u16* zin_cur, const u16* Wih, const u16* Whh, const float* bias_int,
    float* c_ws, u16* zin_nxt, u16* qbuf, u16* outs, int t) {
  int lane = threadIdx.x & 63, wave = threadIdx.x >> 6;
  int col = lane & 15, q = lane >> 4;
  int m0 = blockIdx.x * 64 + (wave >> 1) * 32;
  int n0 = blockIdx.y * 64 + (wave & 1) * 32;
  f32x4 acc[2][2] = {};
  const u16* pA[2]; const u16* pI[2]; const u16* pH[2];
#pragma unroll
  for (int i = 0; i < 2; i++) {
    pA[i] = zin_cur + (size_t)(m0 + i * 16 + col) * 1024 + q * 8;
    int r = n0 + i * 16 + col;
    int src = (r & 3) * 512 + (r >> 2);
    pI[i] = Wih + (size_t)src * 512 + q * 8;
    pH[i] = Whh + (size_t)src * 512 + q * 8;
  }
  for (int k = 0; k < 512; k += 32) {
    bf16x8 a0 = load8(pA[0] + k);
    bf16x8 a1 = load8(pA[1] + k);
    bf16x8 b0 = load8(pI[0] + k);
    bf16x8 b1 = load8(pI[1] + k);
    acc[0][0] = __builtin_amdgcn_mfma_f32_16x16x32_bf16(a0, b0, acc[0][0], 0, 0, 0);
    acc[0][1] = __builtin_amdgcn_mfma_f32_16x16x32_bf16(a0, b1, acc[0][1], 0, 0, 0);
    acc[1][0] = __builtin_amdgcn_mfma_f32_16x16x32_bf16(a1, b0, acc[1][0], 0, 0, 0);
    acc[1][1] = __builtin_amdgcn_mfma_f32_16x16x32_bf16(a1, b1, acc[1][1], 0, 0, 0);
  }
  for (int k = 0; k < 512; k += 32) {
    bf16x8 a0 = load8(pA[0] + 512 + k);
    bf16x8 a1 = load8(pA[1] + 512 + k);
    bf16x8 b0 = load8(pH[0] + k);
    bf16x8 b1 = load8(pH[1] + k);
    acc[0][0] = __builtin_amdgcn_mfma_f32_16x16x32_bf16(a0, b0, acc[0][0], 0, 0, 0);
    acc[0][1] = __builtin_amdgcn_mfma_f32_16x16x32_bf16(a0, b1, acc[0][1], 0, 0, 0);
    acc[1][0] = __builtin_amdgcn_mfma_f32_16x16x32_bf16(a1, b0, acc[1][0], 0, 0, 0);
    acc[1][1] = __builtin_amdgcn_mfma_f32_16x16x32_bf16(a1, b1, acc[1][1], 0, 0, 0);
  }
  __shared__ float ls[64][68];
#pragma unroll
  for (int mi = 0; mi < 2; mi++)
#pragma unroll
    for (int ni = 0; ni < 2; ni++)
#pragma unroll
      for (int r = 0; r < 4; r++) {
        int nl = (wave & 1) * 32 + ni * 16 + col;
        int ml = (wave >> 1) * 32 + mi * 16 + q * 4 + r;
        ls[ml][nl] = acc[mi][ni][r] + bias_int[blockIdx.y * 64 + nl];
      }
  __syncthreads();
  int m = threadIdx.x & 63, grp = threadIdx.x >> 6;
  int gm = blockIdx.x * 64 + m;
  int j0 = blockIdx.y * 16;
#pragma unroll
  for (int jl = 0; jl < 4; jl++) {
    int jc = grp * 4 + jl;
    float gi = ls[m][jc * 4 + 0];
    float gf = ls[m][jc * 4 + 1];
    float gg = ls[m][jc * 4 + 2];
    float go = ls[m][jc * 4 + 3];
    int j = j0 + jc;
    float cn = sigf(gf) * c_ws[gm * 512 + j] + sigf(gi) * tanhf(gg);
    c_ws[gm * 512 + j] = cn;
    float hn = sigf(go) * tanhf(cn);
    u16 hb = f2bf(hn);
    zin_nxt[(size_t)gm * 1024 + 512 + j] = hb;
    qbuf[(size_t)gm * 1024 + j] = hb;
    outs[((size_t)gm * 32 + t) * 512 + j] = hb;
  }
}

// ---------------------------------------------------------------------------
// prep kernels (r4 verbatim)
// ---------------------------------------------------------------------------
struct CvtJob { const float* src; u16* dst; int R; int C; int ld; int c0; int tr; int blk0; };
struct CvtJobs { CvtJob j[15]; int njobs; };

__global__ void cvt_all(CvtJobs a) {
  int bid = blockIdx.x;
  int ji = 0;
  while (ji + 1 < a.njobs && bid >= a.j[ji + 1].blk0) ji++;
  CvtJob jb = a.j[ji];
  int idx = (bid - jb.blk0) * 256 + threadIdx.x;
  int n = jb.R * jb.C;
  if (idx >= n) return;
  int r = idx / jb.C, c = idx - r * jb.C;
  float v = jb.src[(size_t)r * jb.ld + jb.c0 + c];
  if (jb.tr) jb.dst[(size_t)c * jb.R + r] = f2bf(v);
  else jb.dst[idx] = f2bf(v);
}

__global__ void addcvt(const float* a, const float* b, float* o, int n) {
  int i = blockIdx.x * 256 + threadIdx.x;
  if (i < n) o[i] = a[i] + (b ? b[i] : 0.f);
}

__global__ void bdecint_build(const float* bih, const float* bhh, float* o) {
  int r = blockIdx.x * 256 + threadIdx.x; // 2048
  int j = r >> 2, gg = r & 3;
  o[r] = bih[gg * 512 + j] + bhh[gg * 512 + j];
}

__global__ void wsum_build(const float* Wbd, u16* Wsum) {
  int idx = blockIdx.x * 256 + threadIdx.x; // 512*896
  int n = idx / 896, j = idx % 896;
  int c1 = (j < 448) ? (1024 + j) : (1920 + (j - 448));
  int c2 = c1 + 448;
  Wsum[idx] = f2bf(Wbd[(size_t)n * 2944 + c1] + Wbd[(size_t)n * 2944 + c2]);
}

// ---------------------------------------------------------------------------
// Env encoder (r0 verbatim)
// ---------------------------------------------------------------------------
__global__ __launch_bounds__(256) void env_encode(
    const int* cur_env, const int* ini_env,
    const float* color_emb, const float* pos_emb,
    const float* wih, const float* whh, const float* bih, const float* bhh,
    u16* ctx_cat) {
  __shared__ float s_wih[128 * 33], s_whh[128 * 33], s_b[128], s_col[7 * 32];
  __shared__ float h_lds[8][33];
  int tid = threadIdx.x;
  for (int i = tid; i < 128 * 32; i += 256) {
    int r = i >> 5, k2 = i & 31;
    s_wih[r * 33 + k2] = wih[i];
    s_whh[r * 33 + k2] = whh[i];
  }
  for (int i = tid; i < 128; i += 256) s_b[i] = bih[i] + bhh[i];
  for (int i = tid; i < 224; i += 256) s_col[i] = color_emb[i];
  int sl = tid >> 5, j = tid & 31;
  int gseq = blockIdx.x * 8 + sl;
  int e = gseq / 896, rem = gseq % 896;
  int b = rem / 7, p = rem % 7;
  const int* env = e ? ini_env : cur_env;
  int eoff = e ? 0 : 448;
  h_lds[sl][j] = 0.f;
  __syncthreads();
  float cj = 0.f, hj = 0.f;
  for (int st = 0; st < 4; st++) {
    int tok = clampi(env[b * 35 + p * 5 + 1 + st], 0, 6);
    const float* x = &s_col[tok * 32];
    float pi = s_b[j], pf = s_b[32 + j], pg = s_b[64 + j], po = s_b[96 + j];
    for (int k = 0; k < 32; k++) {
      float xk = x[k], hk = h_lds[sl][k];
      pi += s_wih[j * 33 + k] * xk + s_whh[j * 33 + k] * hk;
      pf += s_wih[(32 + j) * 33 + k] * xk + s_whh[(32 + j) * 33 + k] * hk;
      pg += s_wih[(64 + j) * 33 + k] * xk + s_whh[(64 + j) * 33 + k] * hk;
      po += s_wih[(96 + j) * 33 + k] * xk + s_whh[(96 + j) * 33 + k] * hk;
    }
    cj = sigf(pf) * cj + sigf(pi) * tanhf(pg);
    hj = sigf(po) * tanhf(cj);
    __syncthreads();
    h_lds[sl][j] = hj;
    __syncthreads();
  }
  size_t base = (size_t)b * 896 + eoff + p * 64;
  ctx_cat[base + j] = f2bf(pos_emb[p * 32 + j]);
  ctx_cat[base + 32 + j] = f2bf(hj);
}

// ---------------------------------------------------------------------------
// Encoder step v2 (r4 verbatim): h-recurrence MFMA (K=256) + projE gather.
// ---------------------------------------------------------------------------
#define HBUF ((size_t)4 * 128 * 256)
__global__ __launch_bounds__(256) void enc_step2(
    int t, int chainbase,
    const int* ins_tok, const int* his_tok,
    const float* projE_f, const float* projE_b,   // [2000][1024] = emb @ Wih^T
    const u16* whh_f, const u16* whh_b,
    const float* bias_f, const float* bias_b,
    u16* h_enc, float* c_enc,
    u16* ins_enc, u16* his_enc) {
  int chain = chainbase + (blockIdx.x >> 5);
  int sub = blockIdx.x & 31;
  int sgrp = sub >> 2, jq = sub & 3;
  int w = threadIdx.x >> 6, lane = threadIdx.x & 63;
  int col = lane & 15, q = lane >> 4;
  int dir = chain & 1, his = chain >> 1;
  int L = his ? 128 : 64;
  const int* toks = his ? his_tok : ins_tok;
  int t_x = dir ? (L - 1 - t) : t;
  const float* projE = dir ? projE_b : projE_f;
  const u16* whh = dir ? whh_b : whh_f;
  const float* bias = dir ? bias_b : bias_f;
  const u16* h_rd = h_enc + ((size_t)((t & 1) ^ 1)) * HBUF + (size_t)chain * 128 * 256;
  u16* h_wr = h_enc + ((size_t)(t & 1)) * HBUF + (size_t)chain * 128 * 256;
  float* c_g = c_enc + (size_t)chain * 128 * 256;
  u16* out = his ? his_enc : ins_enc;

  int jw = jq * 64 + w * 16;
  f32x4 acc[4] = {};
  if (t > 0) {
    const u16* hrow = h_rd + (size_t)(sgrp * 16 + col) * 256 + q * 8;
    const u16* wrow[4];
#pragma unroll
    for (int G = 0; G < 4; G++) wrow[G] = whh + (size_t)(G * 256 + jw + col) * 256 + q * 8;
    for (int k = 0; k < 256; k += 32) {
      bf16x8 a = load8(hrow + k);
#pragma unroll
      for (int G = 0; G < 4; G++) {
        bf16x8 bb = load8(wrow[G] + k);
        acc[G] = __builtin_amdgcn_mfma_f32_16x16x32_bf16(a, bb, acc[G], 0, 0, 0);
      }
    }
  }
  int j = jw + col;
  float bi = bias[j], bf = bias[256 + j], bg = bias[512 + j], bo = bias[768 + j];
#pragma unroll
  for (int r = 0; r < 4; r++) {
    int s = q * 4 + r;
    int b = sgrp * 16 + s;
    int tok = clampi(toks[b * L + t_x], 0, 1999);
    const float* px = projE + (size_t)tok * 1024;
    float pi = acc[0][r] + px[j] + bi;
    float pf = acc[1][r] + px[256 + j] + bf;
    float pg = acc[2][r] + px[512 + j] + bg;
    float po = acc[3][r] + px[768 + j] + bo;
    float cold = (t > 0) ? c_g[b * 256 + j] : 0.f;
    float cn = sigf(pf) * cold + sigf(pi) * tanhf(pg);
    float hn = sigf(po) * tanhf(cn);
    c_g[b * 256 + j] = cn;
    u16 hb = f2bf(hn);
    h_wr[b * 256 + j] = hb;
    out[((size_t)b * L + t_x) * 512 + dir * 256 + j] = hb;
  }
}

// ---------------------------------------------------------------------------
// Decoder attention 1 (r0 verbatim)
// ---------------------------------------------------------------------------
__global__ __launch_bounds__(256) void attn1(
    const float* u_c, const u16* insenc, u16* qattn, u16* qbuf) {
  int b = blockIdx.x, tid = threadIdx.x;
  __shared__ float su[512], red[256], aw[64];
  for (int d = tid; d < 512; d += 256) su[d] = u_c[b * 512 + d];
  __syncthreads();
  {
    int l = tid >> 2, part = tid & 3;
    const u16* row = insenc + ((size_t)b * 64 + l) * 512 + part * 128;
    float s = 0.f;
    for (int k = 0; k < 128; k += 8) {
      bf16x8 v = load8(row + k);
#pragma unroll
      for (int e = 0; e < 8; e++) s += bf2f((u16)v[e]) * su[part * 128 + k + e];
    }
    red[tid] = s;
  }
  __syncthreads();
  if (tid < 64) {
    float sc = red[tid * 4] + red[tid * 4 + 1] + red[tid * 4 + 2] + red[tid * 4 + 3];
    float m = sc;
    for (int off = 32; off > 0; off >>= 1) m = fmaxf(m, __shfl_xor(m, off));
    float e = __expf(sc - m);
    float sm = e;
    for (int off = 32; off > 0; off >>= 1) sm += __shfl_xor(sm, off);
    aw[tid] = e / sm;
  }
  __syncthreads();
  for (int d = tid; d < 512; d += 256) {
    float z = 0.f;
    for (int l = 0; l < 64; l++) z += aw[l] * bf2f(insenc[((size_t)b * 64 + l) * 512 + d]);
    u16 zb = f2bf(z);
    qattn[(size_t)b * 1024 + d] = zb;
    qbuf[(size_t)b * 1024 + 512 + d] = zb;
  }
}

// ---------------------------------------------------------------------------
// Decoder attention 2 (r0 verbatim)
// ---------------------------------------------------------------------------
__global__ __launch_bounds__(256) void attn2(
    const float* u_p, const u16* hisenc, u16* qattn) {
  int b = blockIdx.x, tid = threadIdx.x;
  __shared__ float su[512], red[256], aw[128], mr[2];
  for (int d = tid; d < 512; d += 256) su[d] = u_p[b * 512 + d];
  __syncthreads();
  {
    int l = tid >> 1, part = tid & 1;
    const u16* row = hisenc + ((size_t)b * 128 + l) * 512 + part * 256;
    float s = 0.f;
    for (int k = 0; k < 256; k += 8) {
      bf16x8 v = load8(row + k);
#pragma unroll
      for (int e = 0; e < 8; e++) s += bf2f((u16)v[e]) * su[part * 256 + k + e];
    }
    red[tid] = s;
  }
  __syncthreads();
  float sc = (tid < 128) ? red[tid * 2] + red[tid * 2 + 1] : 0.f;
  __syncthreads();
  if (tid < 128) red[tid] = sc;
  __syncthreads();
  if (tid < 64) {
    float m = fmaxf(red[tid], red[tid + 64]);
    for (int off = 32; off > 0; off >>= 1) m = fmaxf(m, __shfl_xor(m, off));
    if (tid == 0) mr[0] = m;
  }
  __syncthreads();
  float ex = 0.f;
  if (tid < 128) { ex = __expf(sc - mr[0]); red[tid] = ex; }
  __syncthreads();
  if (tid < 64) {
    float s2 = red[tid] + red[tid + 64];
    for (int off = 32; off > 0; off >>= 1) s2 += __shfl_xor(s2, off);
    if (tid == 0) mr[1] = s2;
  }
  __syncthreads();
  if (tid < 128) aw[tid] = ex / mr[1];
  __syncthreads();
  for (int d = tid; d < 512; d += 256) {
    float z = 0.f;
    for (int l = 0; l < 128; l++) z += aw[l] * bf2f(hisenc[((size_t)b * 128 + l) * 512 + d]);
    qattn[(size_t)b * 1024 + 512 + d] = f2bf(z);
  }
}

// decoder init (r0 verbatim)
__global__ void dec_init(const float* h0, const float* c0, u16* zin0, u16* qbuf, float* c_ws) {
  int idx = blockIdx.x * 256 + threadIdx.x; // 128*512
  int b = idx >> 9, d = idx & 511;
  u16 hv = f2bf(h0[idx]);
  zin0[(size_t)b * 1024 + 512 + d] = hv;
  qbuf[(size_t)b * 1024 + d] = hv;
  c_ws[idx] = c0[idx];
}

// ---------------------------------------------------------------------------
extern "C" void kernel_launch(void* const* d_in, const int* in_sizes, int n_in,
                              void* d_out, int out_size, void* d_ws, size_t ws_size,
                              hipStream_t stream) {
  const int* ins_tok = (const int*)d_in[0];
  const int* his_tok = (const int*)d_in[1];
  const int* actions = (const int*)d_in[2];
  const int* cur_env = (const int*)d_in[3];
  const int* ini_env = (const int*)d_in[4];
  const float* enc_emb = (const float*)d_in[5];
  const float* Wih_f = (const float*)d_in[6];
  const float* Whh_f = (const float*)d_in[7];
  const float* bih_f = (const float*)d_in[8];
  const float* bhh_f = (const float*)d_in[9];
  const float* Wih_b = (const float*)d_in[10];
  const float* Whh_b = (const float*)d_in[11];
  const float* bih_b = (const float*)d_in[12];
  const float* bhh_b = (const float*)d_in[13];
  const float* color_emb = (const float*)d_in[14];
  const float* pos_emb = (const float*)d_in[15];
  const float* ws_Wih = (const float*)d_in[16];
  const float* ws_Whh = (const float*)d_in[17];
  const float* ws_bih = (const float*)d_in[18];
  const float* ws_bhh = (const float*)d_in[19];
  const float* act_emb = (const float*)d_in[20];
  const float* W_c = (const float*)d_in[21];
  const float* W_p = (const float*)d_in[22];
  // d_in[23..26] are mathematically dead (uniform softmax over broadcast rows).
  const float* Wbd_W = (const float*)d_in[27];
  const float* Wbd_b = (const float*)d_in[28];
  const float* dec_Wih = (const float*)d_in[29];
  const float* dec_Whh = (const float*)d_in[30];
  const float* dec_bih = (const float*)d_in[31];
  const float* dec_bhh = (const float*)d_in[32];
  const float* h2a_W = (const float*)d_in[33];
  const float* h2a_b = (const float*)d_in[34];
  const float* h0 = (const float*)d_in[35];
  const float* c0 = (const float*)d_in[36];
  (void)in_sizes; (void)n_in; (void)out_size; (void)ws_size;

  char* ws = (char*)d_ws;
  size_t off = 0;
  auto alloc = [&](size_t bytes) -> char* {
    char* p = ws + off;
    off = (off + bytes + 255) & ~(size_t)255;
    return p;
  };
  u16* insenc   = (u16*)alloc(8192ull * 512 * 2);
  u16* hisenc   = (u16*)alloc(16384ull * 512 * 2);
  u16* outs     = (u16*)alloc(4096ull * 512 * 2);
  u16* Wsum     = (u16*)alloc(512ull * 896 * 2);
  u16* h_enc    = (u16*)alloc(2 * HBUF * 2);
  float* c_enc  = (float*)alloc(4ull * 128 * 256 * 4);
  float* projact= (float*)alloc(100ull * 512 * 4);
  float* bias_f = (float*)alloc(1024 * 4);
  float* bias_b = (float*)alloc(1024 * 4);
  float* bdecint= (float*)alloc(2048 * 4);
  float* bwbd   = (float*)alloc(512 * 4);
  float* bh2a   = (float*)alloc(128 * 4);
  u16* ctxcat   = (u16*)alloc(128ull * 896 * 2);
  float* hkbase = (float*)alloc(128ull * 512 * 4);
  float* u_c    = (float*)alloc(128ull * 512 * 4);
  float* u_p    = (float*)alloc(128ull * 512 * 4);
  u16* qbuf     = (u16*)alloc(128ull * 1024 * 2);     // [h | z_c]
  u16* qattn    = (u16*)alloc(128ull * 1024 * 2);     // [z_c | z_p]
  u16* zin      = (u16*)alloc(2ull * 128 * 1024 * 2); // [hk | h], parity
  float* c_dec  = (float*)alloc(128ull * 512 * 4);
  // x-projection tables: projE = enc_emb @ Wih^T per direction (f32)
  float* projE_f = (float*)alloc(2000ull * 1024 * 4); // 8.2 MB
  float* projE_b = (float*)alloc(2000ull * 1024 * 4); // 8.2 MB
  // bf16 weight copies
  u16* emb_bf   = (u16*)alloc(2000ull * 128 * 2);
  u16* wihf_bf  = (u16*)alloc(1024ull * 128 * 2);
  u16* wihb_bf  = (u16*)alloc(1024ull * 128 * 2);
  u16* whhf_bf  = (u16*)alloc(1024ull * 256 * 2);
  u16* whhb_bf  = (u16*)alloc(1024ull * 256 * 2);
  u16* act_bf   = (u16*)alloc(100ull * 128 * 2);
  u16* wc_bf    = (u16*)alloc(512ull * 512 * 2);
  u16* wp_bf    = (u16*)alloc(512ull * 1024 * 2);
  u16* wbd01_bf = (u16*)alloc(512ull * 1024 * 2);
  u16* wbdx_bf  = (u16*)alloc(512ull * 128 * 2);
  u16* dwih_bf  = (u16*)alloc(2048ull * 512 * 2);
  u16* dwhh_bf  = (u16*)alloc(2048ull * 512 * 2);
  u16* h2a_bf   = (u16*)alloc(100ull * 512 * 2);

  // --- all weight conversions in ONE launch ---
  CvtJobs cj{};
  int nb = 0, jn = 0;
  auto addjob = [&](const float* s, u16* d, int R, int C, int ld, int c0c, int tr) {
    cj.j[jn] = { s, d, R, C, ld, c0c, tr, nb };
    nb += (R * C + 255) / 256;
    jn++;
  };
  addjob(enc_emb, emb_bf, 2000, 128, 128, 0, 0);
  addjob(Wih_f, wihf_bf, 1024, 128, 128, 0, 0);
  addjob(Wih_b, wihb_bf, 1024, 128, 128, 0, 0);
  addjob(Whh_f, whhf_bf, 1024, 256, 256, 0, 0);
  addjob(Whh_b, whhb_bf, 1024, 256, 256, 0, 0);
  addjob(act_emb, act_bf, 100, 128, 128, 0, 0);
  addjob(W_c, wc_bf, 512, 512, 512, 0, 0);
  addjob(W_p, wp_bf, 512, 1024, 1024, 0, 0);
  addjob(Wbd_W, wbd01_bf, 512, 1024, 2944, 0, 0);
  addjob(Wbd_W, wbdx_bf, 512, 128, 2944, 2816, 0);
  addjob(dec_Wih, dwih_bf, 2048, 512, 512, 0, 0);
  addjob(dec_Whh, dwhh_bf, 2048, 512, 512, 0, 0);
  addjob(h2a_W, h2a_bf, 100, 512, 512, 0, 0);
  cj.njobs = jn;
  cvt_all<<<nb, 256, 0, stream>>>(cj);

  // --- bias prep ---
  addcvt<<<4, 256, 0, stream>>>(bih_f, bhh_f, bias_f, 1024);
  addcvt<<<4, 256, 0, stream>>>(bih_b, bhh_b, bias_b, 1024);
  addcvt<<<2, 256, 0, stream>>>(Wbd_b, nullptr, bwbd, 512);
  addcvt<<<1, 256, 0, stream>>>(h2a_b, nullptr, bh2a, 100);
  bdecint_build<<<8, 256, 0, stream>>>(dec_bih, dec_bhh, bdecint);
  wsum_build<<<1792, 256, 0, stream>>>(Wbd_W, Wsum);

  // --- projE tables: emb @ Wih^T per direction (M=2000, N=1024, K=128) ---
  {
    GemmArgs ge = {};
    ge.A = emb_bf; ge.lda = 128; ge.M = 2000; ge.W = wihf_bf; ge.ldw = 128;
    ge.N = 1024; ge.K = 128; ge.out = projE_f; ge.ldc = 1024;
    gemm_k<0><<<dim3(32, 16), 256, 0, stream>>>(ge);
    ge.W = wihb_bf; ge.out = projE_b;
    gemm_k<0><<<dim3(32, 16), 256, 0, stream>>>(ge);
  }

  // --- proj_act = act_emb @ Wbd_x^T + Wbd_b ---
  GemmArgs gp = {};
  gp.A = act_bf; gp.lda = 128; gp.M = 100; gp.W = wbdx_bf; gp.ldw = 128;
  gp.N = 512; gp.K = 128; gp.out = projact; gp.ldc = 512; gp.bias = bwbd;
  gemm_k<0><<<dim3(2, 8), 256, 0, stream>>>(gp);

  // --- env encode + hk_base ---
  env_encode<<<224, 256, 0, stream>>>(cur_env, ini_env, color_emb, pos_emb,
                                      ws_Wih, ws_Whh, ws_bih, ws_bhh, ctxcat);
  GemmArgs gb = {};
  gb.A = ctxcat; gb.lda = 896; gb.M = 128; gb.W = Wsum; gb.ldw = 896;
  gb.N = 512; gb.K = 896; gb.out = hkbase; gb.ldc = 512;
  gemm_k<0><<<dim3(2, 8), 256, 0, stream>>>(gb);

  // --- encoder: 128 sequential steps (projE-gathered x-part, K=256 MFMA) ---
  for (int t = 0; t < 128; t++) {
    int cb = (t < 64) ? 0 : 2;
    int nbk = (t < 64) ? 128 : 64;
    enc_step2<<<nbk, 256, 0, stream>>>(t, cb, ins_tok, his_tok,
                                       projE_f, projE_b, whhf_bf, whhb_bf,
                                       bias_f, bias_b, h_enc, c_enc,
                                       insenc, hisenc);
  }

  // --- decoder: r4 structure; u_c/u_p/hk retiled 32x32 (4x blocks) ---
  dec_init<<<256, 256, 0, stream>>>(h0, c0, zin, qbuf, c_dec);
  for (int t = 0; t < 32; t++) {
    u16* zin_cur = zin + (size_t)(t & 1) * 128 * 1024;
    u16* zin_nxt = zin + (size_t)((t + 1) & 1) * 128 * 1024;
    // u_c = W_c @ h  (M=128,N=512,K=512) -> 4x16 = 64 blocks
    GemmArgs gu = {};
    gu.A = qbuf; gu.lda = 1024; gu.M = 128; gu.W = wc_bf; gu.ldw = 512;
    gu.N = 512; gu.K = 512; gu.out = u_c; gu.ldc = 512;
    gemm32_k<0><<<dim3(4, 16), 256, 0, stream>>>(gu);
    attn1<<<128, 256, 0, stream>>>(u_c, insenc, qattn, qbuf);
    // u_p = W_p @ [h | z_c]  (K=1024) -> 64 blocks
    GemmArgs gv = {};
    gv.A = qbuf; gv.lda = 1024; gv.M = 128; gv.W = wp_bf; gv.ldw = 1024;
    gv.N = 512; gv.K = 1024; gv.out = u_p; gv.ldc = 512;
    gemm32_k<0><<<dim3(4, 16), 256, 0, stream>>>(gv);
    attn2<<<128, 256, 0, stream>>>(u_p, hisenc, qattn);
    // hk = tanh([z_c|z_p]@Wbd[:,0:1024]^T + hk_base + proj_act[action]) -> 64 blocks
    GemmArgs gh = {};
    gh.A = qattn; gh.lda = 1024; gh.M = 128; gh.W = wbd01_bf; gh.ldw = 1024;
    gh.N = 512; gh.K = 1024; gh.out = zin_cur; gh.ldc = 1024;
    gh.hk_base = hkbase; gh.proj_act = projact; gh.actions = actions; gh.t = t;
    gemm32_k<2><<<dim3(4, 16), 256, 0, stream>>>(gh);
    // gates + fused cell (64 blocks, unchanged)
    dec_gates_cell<<<dim3(2, 32), 256, 0, stream>>>(
        zin_cur, dwih_bf, dwhh_bf, bdecint, c_dec, zin_nxt, qbuf, outs, t);
  }

  // --- logits (f32 out): 32x32 tiles -> 128x4 = 512 blocks ---
  GemmArgs gl = {};
  gl.A = outs; gl.lda = 512; gl.M = 4096; gl.W = h2a_bf; gl.ldw = 512;
  gl.N = 100; gl.K = 512; gl.out = d_out; gl.ldc = 100; gl.bias = bh2a;
  gemm32_k<0><<<dim3(128, 4), 256, 0, stream>>>(gl);
}

// Round 8
// 3127.447 us; speedup vs baseline: 3.4806x; 1.2452x over previous
//
#include <hip/hip_runtime.h>

// Seq2Seq round 12 = r7 (3894us) + two applications of the proven
// "widen latency-bound dispatches" lever:
//  - dec_gates_cell retiled 64x64 -> 32x32 tiles (64 -> 256 blocks), fused
//    LSTM cell epilogue reworked for the narrow tile (1 cell/thread).
//  - attn1/attn2 z-phase vectorized: bf16x8 row loads, l-range split across
//    4 thread groups + LDS reduce (was: 64/128-iter scalar-load loop/thread).
// Everything else r7 verbatim.

typedef unsigned short u16;
typedef __attribute__((ext_vector_type(8))) short bf16x8;
typedef __attribute__((ext_vector_type(4))) float f32x4;

#define DEVFN static __device__ __forceinline__

DEVFN float bf2f(u16 u) {
  unsigned int x = ((unsigned int)u) << 16;
  float f; __builtin_memcpy(&f, &x, 4); return f;
}
DEVFN u16 f2bf(float f) {
  unsigned int x; __builtin_memcpy(&x, &f, 4);
  x = (x + 0x7fffu + ((x >> 16) & 1u)) >> 16;
  return (u16)x;
}
DEVFN float sigf(float x) { return 1.f / (1.f + __expf(-x)); }
DEVFN bf16x8 load8(const u16* p) { return *(const bf16x8*)p; }
DEVFN int clampi(int v, int lo, int hi) { return v < lo ? lo : (v > hi ? hi : v); }

// ---------------------------------------------------------------------------
// Generic MFMA GEMM (64x64 block tile). EPI 0: f32 out (+bias).
// ---------------------------------------------------------------------------
struct GemmArgs {
  const u16* A; int lda; int M;
  const u16* W; int ldw; int N; int K;
  void* out; int ldc;
  const float* bias;
  const float* hk_base; const float* proj_act; const int* actions; int t;
};

template <int EPI>
__global__ __launch_bounds__(256) void gemm_k(GemmArgs g) {
  int lane = threadIdx.x & 63;
  int wave = threadIdx.x >> 6;
  int col = lane & 15, q = lane >> 4;
  int m0 = blockIdx.x * 64 + (wave >> 1) * 32;
  int n0 = blockIdx.y * 64 + (wave & 1) * 32;
  f32x4 acc[2][2] = {};
  int rA[2] = { m0 + col, m0 + 16 + col };
  int rB[2] = { n0 + col, n0 + 16 + col };
  bool gA[2] = { rA[0] < g.M, rA[1] < g.M };
  bool gB[2] = { rB[0] < g.N, rB[1] < g.N };
  const u16* pA[2]; const u16* pB[2];
#pragma unroll
  for (int i = 0; i < 2; i++) {
    pA[i] = g.A + (size_t)(gA[i] ? rA[i] : 0) * g.lda + q * 8;
    pB[i] = g.W + (size_t)(gB[i] ? rB[i] : 0) * g.ldw + q * 8;
  }
  bf16x8 zf = {0,0,0,0,0,0,0,0};
  for (int k = 0; k < g.K; k += 32) {
    bf16x8 a0 = gA[0] ? load8(pA[0] + k) : zf;
    bf16x8 a1 = gA[1] ? load8(pA[1] + k) : zf;
    bf16x8 b0 = gB[0] ? load8(pB[0] + k) : zf;
    bf16x8 b1 = gB[1] ? load8(pB[1] + k) : zf;
    acc[0][0] = __builtin_amdgcn_mfma_f32_16x16x32_bf16(a0, b0, acc[0][0], 0, 0, 0);
    acc[0][1] = __builtin_amdgcn_mfma_f32_16x16x32_bf16(a0, b1, acc[0][1], 0, 0, 0);
    acc[1][0] = __builtin_amdgcn_mfma_f32_16x16x32_bf16(a1, b0, acc[1][0], 0, 0, 0);
    acc[1][1] = __builtin_amdgcn_mfma_f32_16x16x32_bf16(a1, b1, acc[1][1], 0, 0, 0);
  }
#pragma unroll
  for (int mi = 0; mi < 2; mi++)
#pragma unroll
    for (int ni = 0; ni < 2; ni++)
#pragma unroll
      for (int r = 0; r < 4; r++) {
        int m = m0 + mi * 16 + q * 4 + r;
        int n = n0 + ni * 16 + col;
        if (m >= g.M || n >= g.N) continue;
        float v = acc[mi][ni][r];
        if (g.bias) v += g.bias[n];
        ((float*)g.out)[(size_t)m * g.ldc + n] = v;
      }
}

// ---------------------------------------------------------------------------
// 32x32-block-tile MFMA GEMM (r7, validated −700us). EPI 0 / EPI 2 (hk).
// ---------------------------------------------------------------------------
template <int EPI>
__global__ __launch_bounds__(256) void gemm32_k(GemmArgs g) {
  int lane = threadIdx.x & 63;
  int wave = threadIdx.x >> 6;
  int col = lane & 15, q = lane >> 4;
  int m0 = blockIdx.x * 32 + (wave >> 1) * 16;
  int n0 = blockIdx.y * 32 + (wave & 1) * 16;
  f32x4 acc = {};
  int rA = m0 + col, rB = n0 + col;
  bool gA = rA < g.M, gB = rB < g.N;
  const u16* pA = g.A + (size_t)(gA ? rA : 0) * g.lda + q * 8;
  const u16* pB = g.W + (size_t)(gB ? rB : 0) * g.ldw + q * 8;
  bf16x8 zf = {0,0,0,0,0,0,0,0};
  for (int k = 0; k < g.K; k += 32) {
    bf16x8 a = gA ? load8(pA + k) : zf;
    bf16x8 b = gB ? load8(pB + k) : zf;
    acc = __builtin_amdgcn_mfma_f32_16x16x32_bf16(a, b, acc, 0, 0, 0);
  }
#pragma unroll
  for (int r = 0; r < 4; r++) {
    int m = m0 + q * 4 + r;
    int n = n0 + col;
    if (m >= g.M || n >= g.N) continue;
    float v = acc[r];
    if constexpr (EPI == 0) {
      if (g.bias) v += g.bias[n];
      ((float*)g.out)[(size_t)m * g.ldc + n] = v;
    } else {
      int act = clampi(g.actions[m * 32 + g.t], 0, 99);
      v += g.hk_base[m * 512 + n] + g.proj_act[(size_t)act * 512 + n];
      ((u16*)g.out)[(size_t)m * g.ldc + n] = f2bf(tanhf(v));
    }
  }
}

// ---------------------------------------------------------------------------
// Decoder gates GEMM + fused LSTM cell, 32x32 tiles: grid dim3(4, 64) = 256
// blocks (was 64). Block: 32 batch rows x 32 interleaved gate rows
// (= 8 hidden cols x 4 gates). Cell epilogue: 1 cell/thread.
// ---------------------------------------------------------------------------
__global__ __launch_bounds__(256) void dec_gates_cell32(
    const u16* zin_cur, const u16* Wih, const u16* Whh, const float* bias_int,
    float* c_ws, u16* zin_nxt, u16* qbuf, u16* outs, int t) {
  int lane = threadIdx.x & 63, wave = threadIdx.x >> 6;
  int col = lane & 15, q = lane >> 4;
  int m0 = blockIdx.x * 32 + (wave >> 1) * 16;
  int n0 = blockIdx.y * 32 + (wave & 1) * 16;
  f32x4 acc = {};
  const u16* pA = zin_cur + (size_t)(m0 + col) * 1024 + q * 8;
  int r = n0 + col;                       // global interleaved gate row
  int src = (r & 3) * 512 + (r >> 2);     // dec weight row (gate-major)
  const u16* pI = Wih + (size_t)src * 512 + q * 8;
  const u16* pH = Whh + (size_t)src * 512 + q * 8;
  for (int k = 0; k < 512; k += 32) {
    acc = __builtin_amdgcn_mfma_f32_16x16x32_bf16(load8(pA + k), load8(pI + k), acc, 0, 0, 0);
  }
  for (int k = 0; k < 512; k += 32) {
    acc = __builtin_amdgcn_mfma_f32_16x16x32_bf16(load8(pA + 512 + k), load8(pH + k), acc, 0, 0, 0);
  }
  __shared__ float ls[32][36];
#pragma unroll
  for (int rr = 0; rr < 4; rr++) {
    int ml = (wave >> 1) * 16 + q * 4 + rr;
    int nl = (wave & 1) * 16 + col;
    ls[ml][nl] = acc[rr] + bias_int[blockIdx.y * 32 + nl];
  }
  __syncthreads();
  // cell: 32 m x 8 hidden cols = 256 cells, 1/thread
  int m = threadIdx.x & 31, jloc = threadIdx.x >> 5;   // jloc 0..7
  int gm = blockIdx.x * 32 + m;
  int j = blockIdx.y * 8 + jloc;
  float gi = ls[m][jloc * 4 + 0];
  float gf = ls[m][jloc * 4 + 1];
  float gg = ls[m][jloc * 4 + 2];
  float go = ls[m][jloc * 4 + 3];
  float cn = sigf(gf) * c_ws[gm * 512 + j] + sigf(gi) * tanhf(gg);
  c_ws[gm * 512 + j] = cn;
  float hn = sigf(go) * tanhf(cn);
  u16 hb = f2bf(hn);
  zin_nxt[(size_t)gm * 1024 + 512 + j] = hb;
  qbuf[(size_t)gm * 1024 + j] = hb;
  outs[((size_t)gm * 32 + t) * 512 + j] = hb;
}

// ---------------------------------------------------------------------------
// prep kernels (r4 verbatim)
// ---------------------------------------------------------------------------
struct CvtJob { const float* src; u16* dst; int R; int C; int ld; int c0; int tr; int blk0; };
struct CvtJobs { CvtJob j[15]; int njobs; };

__global__ void cvt_all(CvtJobs a) {
  int bid = blockIdx.x;
  int ji = 0;
  while (ji + 1 < a.njobs && bid >= a.j[ji + 1].blk0) ji++;
  CvtJob jb = a.j[ji];
  int idx = (bid - jb.blk0) * 256 + threadIdx.x;
  int n = jb.R * jb.C;
  if (idx >= n) return;
  int r = idx / jb.C, c = idx - r * jb.C;
  float v = jb.src[(size_t)r * jb.ld + jb.c0 + c];
  if (jb.tr) jb.dst[(size_t)c * jb.R + r] = f2bf(v);
  else jb.dst[idx] = f2bf(v);
}

__global__ void addcvt(const float* a, const float* b, float* o, int n) {
  int i = blockIdx.x * 256 + threadIdx.x;
  if (i < n) o[i] = a[i] + (b ? b[i] : 0.f);
}

__global__ void bdecint_build(const float* bih, const float* bhh, float* o) {
  int r = blockIdx.x * 256 + threadIdx.x; // 2048
  int j = r >> 2, gg = r & 3;
  o[r] = bih[gg * 512 + j] + bhh[gg * 512 + j];
}

__global__ void wsum_build(const float* Wbd, u16* Wsum) {
  int idx = blockIdx.x * 256 + threadIdx.x; // 512*896
  int n = idx / 896, j = idx % 896;
  int c1 = (j < 448) ? (1024 + j) : (1920 + (j - 448));
  int c2 = c1 + 448;
  Wsum[idx] = f2bf(Wbd[(size_t)n * 2944 + c1] + Wbd[(size_t)n * 2944 + c2]);
}

// ---------------------------------------------------------------------------
// Env encoder (r0 verbatim)
// ---------------------------------------------------------------------------
__global__ __launch_bounds__(256) void env_encode(
    const int* cur_env, const int* ini_env,
    const float* color_emb, const float* pos_emb,
    const float* wih, const float* whh, const float* bih, const float* bhh,
    u16* ctx_cat) {
  __shared__ float s_wih[128 * 33], s_whh[128 * 33], s_b[128], s_col[7 * 32];
  __shared__ float h_lds[8][33];
  int tid = threadIdx.x;
  for (int i = tid; i < 128 * 32; i += 256) {
    int r = i >> 5, k2 = i & 31;
    s_wih[r * 33 + k2] = wih[i];
    s_whh[r * 33 + k2] = whh[i];
  }
  for (int i = tid; i < 128; i += 256) s_b[i] = bih[i] + bhh[i];
  for (int i = tid; i < 224; i += 256) s_col[i] = color_emb[i];
  int sl = tid >> 5, j = tid & 31;
  int gseq = blockIdx.x * 8 + sl;
  int e = gseq / 896, rem = gseq % 896;
  int b = rem / 7, p = rem % 7;
  const int* env = e ? ini_env : cur_env;
  int eoff = e ? 0 : 448;
  h_lds[sl][j] = 0.f;
  __syncthreads();
  float cj = 0.f, hj = 0.f;
  for (int st = 0; st < 4; st++) {
    int tok = clampi(env[b * 35 + p * 5 + 1 + st], 0, 6);
    const float* x = &s_col[tok * 32];
    float pi = s_b[j], pf = s_b[32 + j], pg = s_b[64 + j], po = s_b[96 + j];
    for (int k = 0; k < 32; k++) {
      float xk = x[k], hk = h_lds[sl][k];
      pi += s_wih[j * 33 + k] * xk + s_whh[j * 33 + k] * hk;
      pf += s_wih[(32 + j) * 33 + k] * xk + s_whh[(32 + j) * 33 + k] * hk;
      pg += s_wih[(64 + j) * 33 + k] * xk + s_whh[(64 + j) * 33 + k] * hk;
      po += s_wih[(96 + j) * 33 + k] * xk + s_whh[(96 + j) * 33 + k] * hk;
    }
    cj = sigf(pf) * cj + sigf(pi) * tanhf(pg);
    hj = sigf(po) * tanhf(cj);
    __syncthreads();
    h_lds[sl][j] = hj;
    __syncthreads();
  }
  size_t base = (size_t)b * 896 + eoff + p * 64;
  ctx_cat[base + j] = f2bf(pos_emb[p * 32 + j]);
  ctx_cat[base + 32 + j] = f2bf(hj);
}

// ---------------------------------------------------------------------------
// Encoder step v2 (r4 verbatim)
// ---------------------------------------------------------------------------
#define HBUF ((size_t)4 * 128 * 256)
__global__ __launch_bounds__(256) void enc_step2(
    int t, int chainbase,
    const int* ins_tok, const int* his_tok,
    const float* projE_f, const float* projE_b,
    const u16* whh_f, const u16* whh_b,
    const float* bias_f, const float* bias_b,
    u16* h_enc, float* c_enc,
    u16* ins_enc, u16* his_enc) {
  int chain = chainbase + (blockIdx.x >> 5);
  int sub = blockIdx.x & 31;
  int sgrp = sub >> 2, jq = sub & 3;
  int w = threadIdx.x >> 6, lane = threadIdx.x & 63;
  int col = lane & 15, q = lane >> 4;
  int dir = chain & 1, his = chain >> 1;
  int L = his ? 128 : 64;
  const int* toks = his ? his_tok : ins_tok;
  int t_x = dir ? (L - 1 - t) : t;
  const float* projE = dir ? projE_b : projE_f;
  const u16* whh = dir ? whh_b : whh_f;
  const float* bias = dir ? bias_b : bias_f;
  const u16* h_rd = h_enc + ((size_t)((t & 1) ^ 1)) * HBUF + (size_t)chain * 128 * 256;
  u16* h_wr = h_enc + ((size_t)(t & 1)) * HBUF + (size_t)chain * 128 * 256;
  float* c_g = c_enc + (size_t)chain * 128 * 256;
  u16* out = his ? his_enc : ins_enc;

  int jw = jq * 64 + w * 16;
  f32x4 acc[4] = {};
  if (t > 0) {
    const u16* hrow = h_rd + (size_t)(sgrp * 16 + col) * 256 + q * 8;
    const u16* wrow[4];
#pragma unroll
    for (int G = 0; G < 4; G++) wrow[G] = whh + (size_t)(G * 256 + jw + col) * 256 + q * 8;
    for (int k = 0; k < 256; k += 32) {
      bf16x8 a = load8(hrow + k);
#pragma unroll
      for (int G = 0; G < 4; G++) {
        bf16x8 bb = load8(wrow[G] + k);
        acc[G] = __builtin_amdgcn_mfma_f32_16x16x32_bf16(a, bb, acc[G], 0, 0, 0);
      }
    }
  }
  int j = jw + col;
  float bi = bias[j], bf = bias[256 + j], bg = bias[512 + j], bo = bias[768 + j];
#pragma unroll
  for (int r = 0; r < 4; r++) {
    int s = q * 4 + r;
    int b = sgrp * 16 + s;
    int tok = clampi(toks[b * L + t_x], 0, 1999);
    const float* px = projE + (size_t)tok * 1024;
    float pi = acc[0][r] + px[j] + bi;
    float pf = acc[1][r] + px[256 + j] + bf;
    float pg = acc[2][r] + px[512 + j] + bg;
    float po = acc[3][r] + px[768 + j] + bo;
    float cold = (t > 0) ? c_g[b * 256 + j] : 0.f;
    float cn = sigf(pf) * cold + sigf(pi) * tanhf(pg);
    float hn = sigf(po) * tanhf(cn);
    c_g[b * 256 + j] = cn;
    u16 hb = f2bf(hn);
    h_wr[b * 256 + j] = hb;
    out[((size_t)b * L + t_x) * 512 + dir * 256 + j] = hb;
  }
}

// ---------------------------------------------------------------------------
// Decoder attention 1 — z-phase vectorized (bf16x8 + 4-way l-split + reduce).
// ---------------------------------------------------------------------------
__global__ __launch_bounds__(256) void attn1(
    const float* u_c, const u16* insenc, u16* qattn, u16* qbuf) {
  int b = blockIdx.x, tid = threadIdx.x;
  __shared__ float su[512], red[256], aw[64];
  __shared__ float zacc[4][512];
  for (int d = tid; d < 512; d += 256) su[d] = u_c[b * 512 + d];
  __syncthreads();
  {
    int l = tid >> 2, part = tid & 3;
    const u16* row = insenc + ((size_t)b * 64 + l) * 512 + part * 128;
    float s = 0.f;
    for (int k = 0; k < 128; k += 8) {
      bf16x8 v = load8(row + k);
#pragma unroll
      for (int e = 0; e < 8; e++) s += bf2f((u16)v[e]) * su[part * 128 + k + e];
    }
    red[tid] = s;
  }
  __syncthreads();
  if (tid < 64) {
    float sc = red[tid * 4] + red[tid * 4 + 1] + red[tid * 4 + 2] + red[tid * 4 + 3];
    float m = sc;
    for (int off = 32; off > 0; off >>= 1) m = fmaxf(m, __shfl_xor(m, off));
    float e = __expf(sc - m);
    float sm = e;
    for (int off = 32; off > 0; off >>= 1) sm += __shfl_xor(sm, off);
    aw[tid] = e / sm;
  }
  __syncthreads();
  // z: part = tid>>6 handles 16 l's; chunk = tid&63 handles 8 d's (vector).
  {
    int part = tid >> 6, chunk = tid & 63;
    float a[8] = {};
    for (int l = part * 16; l < part * 16 + 16; l++) {
      bf16x8 v = load8(insenc + ((size_t)b * 64 + l) * 512 + chunk * 8);
      float w = aw[l];
#pragma unroll
      for (int e = 0; e < 8; e++) a[e] += w * bf2f((u16)v[e]);
    }
#pragma unroll
    for (int e = 0; e < 8; e++) zacc[part][chunk * 8 + e] = a[e];
  }
  __syncthreads();
  for (int d = tid; d < 512; d += 256) {
    float z = zacc[0][d] + zacc[1][d] + zacc[2][d] + zacc[3][d];
    u16 zb = f2bf(z);
    qattn[(size_t)b * 1024 + d] = zb;
    qbuf[(size_t)b * 1024 + 512 + d] = zb;
  }
}

// ---------------------------------------------------------------------------
// Decoder attention 2 — z-phase vectorized (same scheme, 128 l).
// ---------------------------------------------------------------------------
__global__ __launch_bounds__(256) void attn2(
    const float* u_p, const u16* hisenc, u16* qattn) {
  int b = blockIdx.x, tid = threadIdx.x;
  __shared__ float su[512], red[256], aw[128], mr[2];
  __shared__ float zacc[4][512];
  for (int d = tid; d < 512; d += 256) su[d] = u_p[b * 512 + d];
  __syncthreads();
  {
    int l = tid >> 1, part = tid & 1;
    const u16* row = hisenc + ((size_t)b * 128 + l) * 512 + part * 256;
    float s = 0.f;
    for (int k = 0; k < 256; k += 8) {
      bf16x8 v = load8(row + k);
#pragma unroll
      for (int e = 0; e < 8; e++) s += bf2f((u16)v[e]) * su[part * 256 + k + e];
    }
    red[tid] = s;
  }
  __syncthreads();
  float sc = (tid < 128) ? red[tid * 2] + red[tid * 2 + 1] : 0.f;
  __syncthreads();
  if (tid < 128) red[tid] = sc;
  __syncthreads();
  if (tid < 64) {
    float m = fmaxf(red[tid], red[tid + 64]);
    for (int off = 32; off > 0; off >>= 1) m = fmaxf(m, __shfl_xor(m, off));
    if (tid == 0) mr[0] = m;
  }
  __syncthreads();
  float ex = 0.f;
  if (tid < 128) { ex = __expf(sc - mr[0]); red[tid] = ex; }
  __syncthreads();
  if (tid < 64) {
    float s2 = red[tid] + red[tid + 64];
    for (int off = 32; off > 0; off >>= 1) s2 += __shfl_xor(s2, off);
    if (tid == 0) mr[1] = s2;
  }
  __syncthreads();
  if (tid < 128) aw[tid] = ex / mr[1];
  __syncthreads();
  {
    int part = tid >> 6, chunk = tid & 63;
    float a[8] = {};
    for (int l = part * 32; l < part * 32 + 32; l++) {
      bf16x8 v = load8(hisenc + ((size_t)b * 128 + l) * 512 + chunk * 8);
      float w = aw[l];
#pragma unroll
      for (int e = 0; e < 8; e++) a[e] += w * bf2f((u16)v[e]);
    }
#pragma unroll
    for (int e = 0; e < 8; e++) zacc[part][chunk * 8 + e] = a[e];
  }
  __syncthreads();
  for (int d = tid; d < 512; d += 256) {
    float z = zacc[0][d] + zacc[1][d] + zacc[2][d] + zacc[3][d];
    qattn[(size_t)b * 1024 + 512 + d] = f2bf(z);
  }
}

// decoder init (r0 verbatim)
__global__ void dec_init(const float* h0, const float* c0, u16* zin0, u16* qbuf, float* c_ws) {
  int idx = blockIdx.x * 256 + threadIdx.x; // 128*512
  int b = idx >> 9, d = idx & 511;
  u16 hv = f2bf(h0[idx]);
  zin0[(size_t)b * 1024 + 512 + d] = hv;
  qbuf[(size_t)b * 1024 + d] = hv;
  c_ws[idx] = c0[idx];
}

// ---------------------------------------------------------------------------
extern "C" void kernel_launch(void* const* d_in, const int* in_sizes, int n_in,
                              void* d_out, int out_size, void* d_ws, size_t ws_size,
                              hipStream_t stream) {
  const int* ins_tok = (const int*)d_in[0];
  const int* his_tok = (const int*)d_in[1];
  const int* actions = (const int*)d_in[2];
  const int* cur_env = (const int*)d_in[3];
  const int* ini_env = (const int*)d_in[4];
  const float* enc_emb = (const float*)d_in[5];
  const float* Wih_f = (const float*)d_in[6];
  const float* Whh_f = (const float*)d_in[7];
  const float* bih_f = (const float*)d_in[8];
  const float* bhh_f = (const float*)d_in[9];
  const float* Wih_b = (const float*)d_in[10];
  const float* Whh_b = (const float*)d_in[11];
  const float* bih_b = (const float*)d_in[12];
  const float* bhh_b = (const float*)d_in[13];
  const float* color_emb = (const float*)d_in[14];
  const float* pos_emb = (const float*)d_in[15];
  const float* ws_Wih = (const float*)d_in[16];
  const float* ws_Whh = (const float*)d_in[17];
  const float* ws_bih = (const float*)d_in[18];
  const float* ws_bhh = (const float*)d_in[19];
  const float* act_emb = (const float*)d_in[20];
  const float* W_c = (const float*)d_in[21];
  const float* W_p = (const float*)d_in[22];
  // d_in[23..26] are mathematically dead (uniform softmax over broadcast rows).
  const float* Wbd_W = (const float*)d_in[27];
  const float* Wbd_b = (const float*)d_in[28];
  const float* dec_Wih = (const float*)d_in[29];
  const float* dec_Whh = (const float*)d_in[30];
  const float* dec_bih = (const float*)d_in[31];
  const float* dec_bhh = (const float*)d_in[32];
  const float* h2a_W = (const float*)d_in[33];
  const float* h2a_b = (const float*)d_in[34];
  const float* h0 = (const float*)d_in[35];
  const float* c0 = (const float*)d_in[36];
  (void)in_sizes; (void)n_in; (void)out_size; (void)ws_size;

  char* ws = (char*)d_ws;
  size_t off = 0;
  auto alloc = [&](size_t bytes) -> char* {
    char* p = ws + off;
    off = (off + bytes + 255) & ~(size_t)255;
    return p;
  };
  u16* insenc   = (u16*)alloc(8192ull * 512 * 2);
  u16* hisenc   = (u16*)alloc(16384ull * 512 * 2);
  u16* outs     = (u16*)alloc(4096ull * 512 * 2);
  u16* Wsum     = (u16*)alloc(512ull * 896 * 2);
  u16* h_enc    = (u16*)alloc(2 * HBUF * 2);
  float* c_enc  = (float*)alloc(4ull * 128 * 256 * 4);
  float* projact= (float*)alloc(100ull * 512 * 4);
  float* bias_f = (float*)alloc(1024 * 4);
  float* bias_b = (float*)alloc(1024 * 4);
  float* bdecint= (float*)alloc(2048 * 4);
  float* bwbd   = (float*)alloc(512 * 4);
  float* bh2a   = (float*)alloc(128 * 4);
  u16* ctxcat   = (u16*)alloc(128ull * 896 * 2);
  float* hkbase = (float*)alloc(128ull * 512 * 4);
  float* u_c    = (float*)alloc(128ull * 512 * 4);
  float* u_p    = (float*)alloc(128ull * 512 * 4);
  u16* qbuf     = (u16*)alloc(128ull * 1024 * 2);     // [h | z_c]
  u16* qattn    = (u16*)alloc(128ull * 1024 * 2);     // [z_c | z_p]
  u16* zin      = (u16*)alloc(2ull * 128 * 1024 * 2); // [hk | h], parity
  float* c_dec  = (float*)alloc(128ull * 512 * 4);
  // x-projection tables: projE = enc_emb @ Wih^T per direction (f32)
  float* projE_f = (float*)alloc(2000ull * 1024 * 4); // 8.2 MB
  float* projE_b = (float*)alloc(2000ull * 1024 * 4); // 8.2 MB
  // bf16 weight copies
  u16* emb_bf   = (u16*)alloc(2000ull * 128 * 2);
  u16* wihf_bf  = (u16*)alloc(1024ull * 128 * 2);
  u16* wihb_bf  = (u16*)alloc(1024ull * 128 * 2);
  u16* whhf_bf  = (u16*)alloc(1024ull * 256 * 2);
  u16* whhb_bf  = (u16*)alloc(1024ull * 256 * 2);
  u16* act_bf   = (u16*)alloc(100ull * 128 * 2);
  u16* wc_bf    = (u16*)alloc(512ull * 512 * 2);
  u16* wp_bf    = (u16*)alloc(512ull * 1024 * 2);
  u16* wbd01_bf = (u16*)alloc(512ull * 1024 * 2);
  u16* wbdx_bf  = (u16*)alloc(512ull * 128 * 2);
  u16* dwih_bf  = (u16*)alloc(2048ull * 512 * 2);
  u16* dwhh_bf  = (u16*)alloc(2048ull * 512 * 2);
  u16* h2a_bf   = (u16*)alloc(100ull * 512 * 2);

  // --- all weight conversions in ONE launch ---
  CvtJobs cj{};
  int nb = 0, jn = 0;
  auto addjob = [&](const float* s, u16* d, int R, int C, int ld, int c0c, int tr) {
    cj.j[jn] = { s, d, R, C, ld, c0c, tr, nb };
    nb += (R * C + 255) / 256;
    jn++;
  };
  addjob(enc_emb, emb_bf, 2000, 128, 128, 0, 0);
  addjob(Wih_f, wihf_bf, 1024, 128, 128, 0, 0);
  addjob(Wih_b, wihb_bf, 1024, 128, 128, 0, 0);
  addjob(Whh_f, whhf_bf, 1024, 256, 256, 0, 0);
  addjob(Whh_b, whhb_bf, 1024, 256, 256, 0, 0);
  addjob(act_emb, act_bf, 100, 128, 128, 0, 0);
  addjob(W_c, wc_bf, 512, 512, 512, 0, 0);
  addjob(W_p, wp_bf, 512, 1024, 1024, 0, 0);
  addjob(Wbd_W, wbd01_bf, 512, 1024, 2944, 0, 0);
  addjob(Wbd_W, wbdx_bf, 512, 128, 2944, 2816, 0);
  addjob(dec_Wih, dwih_bf, 2048, 512, 512, 0, 0);
  addjob(dec_Whh, dwhh_bf, 2048, 512, 512, 0, 0);
  addjob(h2a_W, h2a_bf, 100, 512, 512, 0, 0);
  cj.njobs = jn;
  cvt_all<<<nb, 256, 0, stream>>>(cj);

  // --- bias prep ---
  addcvt<<<4, 256, 0, stream>>>(bih_f, bhh_f, bias_f, 1024);
  addcvt<<<4, 256, 0, stream>>>(bih_b, bhh_b, bias_b, 1024);
  addcvt<<<2, 256, 0, stream>>>(Wbd_b, nullptr, bwbd, 512);
  addcvt<<<1, 256, 0, stream>>>(h2a_b, nullptr, bh2a, 100);
  bdecint_build<<<8, 256, 0, stream>>>(dec_bih, dec_bhh, bdecint);
  wsum_build<<<1792, 256, 0, stream>>>(Wbd_W, Wsum);

  // --- projE tables: emb @ Wih^T per direction (M=2000, N=1024, K=128) ---
  {
    GemmArgs ge = {};
    ge.A = emb_bf; ge.lda = 128; ge.M = 2000; ge.W = wihf_bf; ge.ldw = 128;
    ge.N = 1024; ge.K = 128; ge.out = projE_f; ge.ldc = 1024;
    gemm_k<0><<<dim3(32, 16), 256, 0, stream>>>(ge);
    ge.W = wihb_bf; ge.out = projE_b;
    gemm_k<0><<<dim3(32, 16), 256, 0, stream>>>(ge);
  }

  // --- proj_act = act_emb @ Wbd_x^T + Wbd_b ---
  GemmArgs gp = {};
  gp.A = act_bf; gp.lda = 128; gp.M = 100; gp.W = wbdx_bf; gp.ldw = 128;
  gp.N = 512; gp.K = 128; gp.out = projact; gp.ldc = 512; gp.bias = bwbd;
  gemm_k<0><<<dim3(2, 8), 256, 0, stream>>>(gp);

  // --- env encode + hk_base ---
  env_encode<<<224, 256, 0, stream>>>(cur_env, ini_env, color_emb, pos_emb,
                                      ws_Wih, ws_Whh, ws_bih, ws_bhh, ctxcat);
  GemmArgs gb = {};
  gb.A = ctxcat; gb.lda = 896; gb.M = 128; gb.W = Wsum; gb.ldw = 896;
  gb.N = 512; gb.K = 896; gb.out = hkbase; gb.ldc = 512;
  gemm_k<0><<<dim3(2, 8), 256, 0, stream>>>(gb);

  // --- encoder: 128 sequential steps ---
  for (int t = 0; t < 128; t++) {
    int cb = (t < 64) ? 0 : 2;
    int nbk = (t < 64) ? 128 : 64;
    enc_step2<<<nbk, 256, 0, stream>>>(t, cb, ins_tok, his_tok,
                                       projE_f, projE_b, whhf_bf, whhb_bf,
                                       bias_f, bias_b, h_enc, c_enc,
                                       insenc, hisenc);
  }

  // --- decoder: r7 structure; gates retiled 32x32 (256 blocks) ---
  dec_init<<<256, 256, 0, stream>>>(h0, c0, zin, qbuf, c_dec);
  for (int t = 0; t < 32; t++) {
    u16* zin_cur = zin + (size_t)(t & 1) * 128 * 1024;
    u16* zin_nxt = zin + (size_t)((t + 1) & 1) * 128 * 1024;
    // u_c = W_c @ h  (M=128,N=512,K=512) -> 64 blocks
    GemmArgs gu = {};
    gu.A = qbuf; gu.lda = 1024; gu.M = 128; gu.W = wc_bf; gu.ldw = 512;
    gu.N = 512; gu.K = 512; gu.out = u_c; gu.ldc = 512;
    gemm32_k<0><<<dim3(4, 16), 256, 0, stream>>>(gu);
    attn1<<<128, 256, 0, stream>>>(u_c, insenc, qattn, qbuf);
    // u_p = W_p @ [h | z_c]  (K=1024) -> 64 blocks
    GemmArgs gv = {};
    gv.A = qbuf; gv.lda = 1024; gv.M = 128; gv.W = wp_bf; gv.ldw = 1024;
    gv.N = 512; gv.K = 1024; gv.out = u_p; gv.ldc = 512;
    gemm32_k<0><<<dim3(4, 16), 256, 0, stream>>>(gv);
    attn2<<<128, 256, 0, stream>>>(u_p, hisenc, qattn);
    // hk -> 64 blocks
    GemmArgs gh = {};
    gh.A = qattn; gh.lda = 1024; gh.M = 128; gh.W = wbd01_bf; gh.ldw = 1024;
    gh.N = 512; gh.K = 1024; gh.out = zin_cur; gh.ldc = 1024;
    gh.hk_base = hkbase; gh.proj_act = projact; gh.actions = actions; gh.t = t;
    gemm32_k<2><<<dim3(4, 16), 256, 0, stream>>>(gh);
    // gates + fused cell: 32x32 tiles -> 256 blocks (was 64)
    dec_gates_cell32<<<dim3(4, 64), 256, 0, stream>>>(
        zin_cur, dwih_bf, dwhh_bf, bdecint, c_dec, zin_nxt, qbuf, outs, t);
  }

  // --- logits (f32 out): 32x32 tiles -> 512 blocks ---
  GemmArgs gl = {};
  gl.A = outs; gl.lda = 512; gl.M = 4096; gl.W = h2a_bf; gl.ldw = 512;
  gl.N = 100; gl.K = 512; gl.out = d_out; gl.ldc = 100; gl.bias = bh2a;
  gemm32_k<0><<<dim3(128, 4), 256, 0, stream>>>(gl);
}

// Round 9
// 2716.018 us; speedup vs baseline: 4.0078x; 1.1515x over previous
//
#include <hip/hip_runtime.h>

// Seq2Seq round 13 = r8 (3127us) + three cuts:
//  - A_c = insenc @ W_c precomputed once (r1-proven numerics) -> u_c GEMM
//    eliminated from the decoder step (6 -> 5 dispatches/step).
//  - enc_step3: 128-thread blocks (2 waves x 32 gate-cols) -> 256/128 blocks
//    per step (was 128/64). Same per-thread work, 2x CUs covering latency.
//  - prep_small: 5 tiny bias-prep kernels fused into 1.

typedef unsigned short u16;
typedef __attribute__((ext_vector_type(8))) short bf16x8;
typedef __attribute__((ext_vector_type(4))) float f32x4;

#define DEVFN static __device__ __forceinline__

DEVFN float bf2f(u16 u) {
  unsigned int x = ((unsigned int)u) << 16;
  float f; __builtin_memcpy(&f, &x, 4); return f;
}
DEVFN u16 f2bf(float f) {
  unsigned int x; __builtin_memcpy(&x, &f, 4);
  x = (x + 0x7fffu + ((x >> 16) & 1u)) >> 16;
  return (u16)x;
}
DEVFN float sigf(float x) { return 1.f / (1.f + __expf(-x)); }
DEVFN bf16x8 load8(const u16* p) { return *(const bf16x8*)p; }
DEVFN int clampi(int v, int lo, int hi) { return v < lo ? lo : (v > hi ? hi : v); }

// ---------------------------------------------------------------------------
// Generic MFMA GEMM (64x64 block tile). EPI 0: f32 (+bias). EPI 1: bf16.
// ---------------------------------------------------------------------------
struct GemmArgs {
  const u16* A; int lda; int M;
  const u16* W; int ldw; int N; int K;
  void* out; int ldc;
  const float* bias;
  const float* hk_base; const float* proj_act; const int* actions; int t;
};

template <int EPI>
__global__ __launch_bounds__(256) void gemm_k(GemmArgs g) {
  int lane = threadIdx.x & 63;
  int wave = threadIdx.x >> 6;
  int col = lane & 15, q = lane >> 4;
  int m0 = blockIdx.x * 64 + (wave >> 1) * 32;
  int n0 = blockIdx.y * 64 + (wave & 1) * 32;
  f32x4 acc[2][2] = {};
  int rA[2] = { m0 + col, m0 + 16 + col };
  int rB[2] = { n0 + col, n0 + 16 + col };
  bool gA[2] = { rA[0] < g.M, rA[1] < g.M };
  bool gB[2] = { rB[0] < g.N, rB[1] < g.N };
  const u16* pA[2]; const u16* pB[2];
#pragma unroll
  for (int i = 0; i < 2; i++) {
    pA[i] = g.A + (size_t)(gA[i] ? rA[i] : 0) * g.lda + q * 8;
    pB[i] = g.W + (size_t)(gB[i] ? rB[i] : 0) * g.ldw + q * 8;
  }
  bf16x8 zf = {0,0,0,0,0,0,0,0};
  for (int k = 0; k < g.K; k += 32) {
    bf16x8 a0 = gA[0] ? load8(pA[0] + k) : zf;
    bf16x8 a1 = gA[1] ? load8(pA[1] + k) : zf;
    bf16x8 b0 = gB[0] ? load8(pB[0] + k) : zf;
    bf16x8 b1 = gB[1] ? load8(pB[1] + k) : zf;
    acc[0][0] = __builtin_amdgcn_mfma_f32_16x16x32_bf16(a0, b0, acc[0][0], 0, 0, 0);
    acc[0][1] = __builtin_amdgcn_mfma_f32_16x16x32_bf16(a0, b1, acc[0][1], 0, 0, 0);
    acc[1][0] = __builtin_amdgcn_mfma_f32_16x16x32_bf16(a1, b0, acc[1][0], 0, 0, 0);
    acc[1][1] = __builtin_amdgcn_mfma_f32_16x16x32_bf16(a1, b1, acc[1][1], 0, 0, 0);
  }
#pragma unroll
  for (int mi = 0; mi < 2; mi++)
#pragma unroll
    for (int ni = 0; ni < 2; ni++)
#pragma unroll
      for (int r = 0; r < 4; r++) {
        int m = m0 + mi * 16 + q * 4 + r;
        int n = n0 + ni * 16 + col;
        if (m >= g.M || n >= g.N) continue;
        float v = acc[mi][ni][r];
        if constexpr (EPI == 0) {
          if (g.bias) v += g.bias[n];
          ((float*)g.out)[(size_t)m * g.ldc + n] = v;
        } else {
          ((u16*)g.out)[(size_t)m * g.ldc + n] = f2bf(v);
        }
      }
}

// ---------------------------------------------------------------------------
// 32x32-block-tile MFMA GEMM (r7/r8 validated). EPI 0 / EPI 2 (hk).
// ---------------------------------------------------------------------------
template <int EPI>
__global__ __launch_bounds__(256) void gemm32_k(GemmArgs g) {
  int lane = threadIdx.x & 63;
  int wave = threadIdx.x >> 6;
  int col = lane & 15, q = lane >> 4;
  int m0 = blockIdx.x * 32 + (wave >> 1) * 16;
  int n0 = blockIdx.y * 32 + (wave & 1) * 16;
  f32x4 acc = {};
  int rA = m0 + col, rB = n0 + col;
  bool gA = rA < g.M, gB = rB < g.N;
  const u16* pA = g.A + (size_t)(gA ? rA : 0) * g.lda + q * 8;
  const u16* pB = g.W + (size_t)(gB ? rB : 0) * g.ldw + q * 8;
  bf16x8 zf = {0,0,0,0,0,0,0,0};
  for (int k = 0; k < g.K; k += 32) {
    bf16x8 a = gA ? load8(pA + k) : zf;
    bf16x8 b = gB ? load8(pB + k) : zf;
    acc = __builtin_amdgcn_mfma_f32_16x16x32_bf16(a, b, acc, 0, 0, 0);
  }
#pragma unroll
  for (int r = 0; r < 4; r++) {
    int m = m0 + q * 4 + r;
    int n = n0 + col;
    if (m >= g.M || n >= g.N) continue;
    float v = acc[r];
    if constexpr (EPI == 0) {
      if (g.bias) v += g.bias[n];
      ((float*)g.out)[(size_t)m * g.ldc + n] = v;
    } else {
      int act = clampi(g.actions[m * 32 + g.t], 0, 99);
      v += g.hk_base[m * 512 + n] + g.proj_act[(size_t)act * 512 + n];
      ((u16*)g.out)[(size_t)m * g.ldc + n] = f2bf(tanhf(v));
    }
  }
}

// ---------------------------------------------------------------------------
// Decoder gates GEMM + fused LSTM cell, 32x32 tiles (r8 verbatim).
// ---------------------------------------------------------------------------
__global__ __launch_bounds__(256) void dec_gates_cell32(
    const u16* zin_cur, const u16* Wih, const u16* Whh, const float* bias_int,
    float* c_ws, u16* zin_nxt, u16* qbuf, u16* outs, int t) {
  int lane = threadIdx.x & 63, wave = threadIdx.x >> 6;
  int col = lane & 15, q = lane >> 4;
  int m0 = blockIdx.x * 32 + (wave >> 1) * 16;
  int n0 = blockIdx.y * 32 + (wave & 1) * 16;
  f32x4 acc = {};
  const u16* pA = zin_cur + (size_t)(m0 + col) * 1024 + q * 8;
  int r = n0 + col;
  int src = (r & 3) * 512 + (r >> 2);
  const u16* pI = Wih + (size_t)src * 512 + q * 8;
  const u16* pH = Whh + (size_t)src * 512 + q * 8;
  for (int k = 0; k < 512; k += 32) {
    acc = __builtin_amdgcn_mfma_f32_16x16x32_bf16(load8(pA + k), load8(pI + k), acc, 0, 0, 0);
  }
  for (int k = 0; k < 512; k += 32) {
    acc = __builtin_amdgcn_mfma_f32_16x16x32_bf16(load8(pA + 512 + k), load8(pH + k), acc, 0, 0, 0);
  }
  __shared__ float ls[32][36];
#pragma unroll
  for (int rr = 0; rr < 4; rr++) {
    int ml = (wave >> 1) * 16 + q * 4 + rr;
    int nl = (wave & 1) * 16 + col;
    ls[ml][nl] = acc[rr] + bias_int[blockIdx.y * 32 + nl];
  }
  __syncthreads();
  int m = threadIdx.x & 31, jloc = threadIdx.x >> 5;
  int gm = blockIdx.x * 32 + m;
  int j = blockIdx.y * 8 + jloc;
  float gi = ls[m][jloc * 4 + 0];
  float gf = ls[m][jloc * 4 + 1];
  float gg = ls[m][jloc * 4 + 2];
  float go = ls[m][jloc * 4 + 3];
  float cn = sigf(gf) * c_ws[gm * 512 + j] + sigf(gi) * tanhf(gg);
  c_ws[gm * 512 + j] = cn;
  float hn = sigf(go) * tanhf(cn);
  u16 hb = f2bf(hn);
  zin_nxt[(size_t)gm * 1024 + 512 + j] = hb;
  qbuf[(size_t)gm * 1024 + j] = hb;
  outs[((size_t)gm * 32 + t) * 512 + j] = hb;
}

// ---------------------------------------------------------------------------
// prep kernels
// ---------------------------------------------------------------------------
struct CvtJob { const float* src; u16* dst; int R; int C; int ld; int c0; int tr; int blk0; };
struct CvtJobs { CvtJob j[15]; int njobs; };

__global__ void cvt_all(CvtJobs a) {
  int bid = blockIdx.x;
  int ji = 0;
  while (ji + 1 < a.njobs && bid >= a.j[ji + 1].blk0) ji++;
  CvtJob jb = a.j[ji];
  int idx = (bid - jb.blk0) * 256 + threadIdx.x;
  int n = jb.R * jb.C;
  if (idx >= n) return;
  int r = idx / jb.C, c = idx - r * jb.C;
  float v = jb.src[(size_t)r * jb.ld + jb.c0 + c];
  if (jb.tr) jb.dst[(size_t)c * jb.R + r] = f2bf(v);
  else jb.dst[idx] = f2bf(v);
}

// fused bias prep: bias_f | bias_b | bwbd | bh2a | bdecint  (4708 elems)
__global__ void prep_small(
    const float* bih_f, const float* bhh_f, float* bias_f,
    const float* bih_b, const float* bhh_b, float* bias_b,
    const float* Wbd_b, float* bwbd,
    const float* h2a_b, float* bh2a,
    const float* dec_bih, const float* dec_bhh, float* bdecint) {
  int i = blockIdx.x * 256 + threadIdx.x;
  if (i < 1024) bias_f[i] = bih_f[i] + bhh_f[i];
  else if (i < 2048) { int k = i - 1024; bias_b[k] = bih_b[k] + bhh_b[k]; }
  else if (i < 2560) { int k = i - 2048; bwbd[k] = Wbd_b[k]; }
  else if (i < 2660) { int k = i - 2560; bh2a[k] = h2a_b[k]; }
  else if (i < 4708) {
    int r = i - 2660;
    int j = r >> 2, gg = r & 3;
    bdecint[r] = dec_bih[gg * 512 + j] + dec_bhh[gg * 512 + j];
  }
}

__global__ void wsum_build(const float* Wbd, u16* Wsum) {
  int idx = blockIdx.x * 256 + threadIdx.x; // 512*896
  int n = idx / 896, j = idx % 896;
  int c1 = (j < 448) ? (1024 + j) : (1920 + (j - 448));
  int c2 = c1 + 448;
  Wsum[idx] = f2bf(Wbd[(size_t)n * 2944 + c1] + Wbd[(size_t)n * 2944 + c2]);
}

// ---------------------------------------------------------------------------
// Env encoder (r0 verbatim)
// ---------------------------------------------------------------------------
__global__ __launch_bounds__(256) void env_encode(
    const int* cur_env, const int* ini_env,
    const float* color_emb, const float* pos_emb,
    const float* wih, const float* whh, const float* bih, const float* bhh,
    u16* ctx_cat) {
  __shared__ float s_wih[128 * 33], s_whh[128 * 33], s_b[128], s_col[7 * 32];
  __shared__ float h_lds[8][33];
  int tid = threadIdx.x;
  for (int i = tid; i < 128 * 32; i += 256) {
    int r = i >> 5, k2 = i & 31;
    s_wih[r * 33 + k2] = wih[i];
    s_whh[r * 33 + k2] = whh[i];
  }
  for (int i = tid; i < 128; i += 256) s_b[i] = bih[i] + bhh[i];
  for (int i = tid; i < 224; i += 256) s_col[i] = color_emb[i];
  int sl = tid >> 5, j = tid & 31;
  int gseq = blockIdx.x * 8 + sl;
  int e = gseq / 896, rem = gseq % 896;
  int b = rem / 7, p = rem % 7;
  const int* env = e ? ini_env : cur_env;
  int eoff = e ? 0 : 448;
  h_lds[sl][j] = 0.f;
  __syncthreads();
  float cj = 0.f, hj = 0.f;
  for (int st = 0; st < 4; st++) {
    int tok = clampi(env[b * 35 + p * 5 + 1 + st], 0, 6);
    const float* x = &s_col[tok * 32];
    float pi = s_b[j], pf = s_b[32 + j], pg = s_b[64 + j], po = s_b[96 + j];
    for (int k = 0; k < 32; k++) {
      float xk = x[k], hk = h_lds[sl][k];
      pi += s_wih[j * 33 + k] * xk + s_whh[j * 33 + k] * hk;
      pf += s_wih[(32 + j) * 33 + k] * xk + s_whh[(32 + j) * 33 + k] * hk;
      pg += s_wih[(64 + j) * 33 + k] * xk + s_whh[(64 + j) * 33 + k] * hk;
      po += s_wih[(96 + j) * 33 + k] * xk + s_whh[(96 + j) * 33 + k] * hk;
    }
    cj = sigf(pf) * cj + sigf(pi) * tanhf(pg);
    hj = sigf(po) * tanhf(cj);
    __syncthreads();
    h_lds[sl][j] = hj;
    __syncthreads();
  }
  size_t base = (size_t)b * 896 + eoff + p * 64;
  ctx_cat[base + j] = f2bf(pos_emb[p * 32 + j]);
  ctx_cat[base + 32 + j] = f2bf(hj);
}

// ---------------------------------------------------------------------------
// Encoder step v3: 128-thread blocks (2 waves x 16 gate-cols x 4 gates).
// Grid: nchains * 64 blocks (sgrp 0..7 x jq 0..7). Same per-thread work as
// enc_step2; 2x the blocks -> 2x CUs covering load latency.
// ---------------------------------------------------------------------------
#define HBUF ((size_t)4 * 128 * 256)
__global__ __launch_bounds__(128) void enc_step3(
    int t, int chainbase,
    const int* ins_tok, const int* his_tok,
    const float* projE_f, const float* projE_b,
    const u16* whh_f, const u16* whh_b,
    const float* bias_f, const float* bias_b,
    u16* h_enc, float* c_enc,
    u16* ins_enc, u16* his_enc) {
  int chain = chainbase + (blockIdx.x >> 6);
  int sub = blockIdx.x & 63;
  int sgrp = sub >> 3, jq = sub & 7;
  int w = threadIdx.x >> 6, lane = threadIdx.x & 63;   // w: 0..1
  int col = lane & 15, q = lane >> 4;
  int dir = chain & 1, his = chain >> 1;
  int L = his ? 128 : 64;
  const int* toks = his ? his_tok : ins_tok;
  int t_x = dir ? (L - 1 - t) : t;
  const float* projE = dir ? projE_b : projE_f;
  const u16* whh = dir ? whh_b : whh_f;
  const float* bias = dir ? bias_b : bias_f;
  const u16* h_rd = h_enc + ((size_t)((t & 1) ^ 1)) * HBUF + (size_t)chain * 128 * 256;
  u16* h_wr = h_enc + ((size_t)(t & 1)) * HBUF + (size_t)chain * 128 * 256;
  float* c_g = c_enc + (size_t)chain * 128 * 256;
  u16* out = his ? his_enc : ins_enc;

  int jw = jq * 32 + w * 16;
  f32x4 acc[4] = {};
  if (t > 0) {
    const u16* hrow = h_rd + (size_t)(sgrp * 16 + col) * 256 + q * 8;
    const u16* wrow[4];
#pragma unroll
    for (int G = 0; G < 4; G++) wrow[G] = whh + (size_t)(G * 256 + jw + col) * 256 + q * 8;
    for (int k = 0; k < 256; k += 32) {
      bf16x8 a = load8(hrow + k);
#pragma unroll
      for (int G = 0; G < 4; G++) {
        bf16x8 bb = load8(wrow[G] + k);
        acc[G] = __builtin_amdgcn_mfma_f32_16x16x32_bf16(a, bb, acc[G], 0, 0, 0);
      }
    }
  }
  int j = jw + col;
  float bi = bias[j], bf = bias[256 + j], bg = bias[512 + j], bo = bias[768 + j];
#pragma unroll
  for (int r = 0; r < 4; r++) {
    int s = q * 4 + r;
    int b = sgrp * 16 + s;
    int tok = clampi(toks[b * L + t_x], 0, 1999);
    const float* px = projE + (size_t)tok * 1024;
    float pi = acc[0][r] + px[j] + bi;
    float pf = acc[1][r] + px[256 + j] + bf;
    float pg = acc[2][r] + px[512 + j] + bg;
    float po = acc[3][r] + px[768 + j] + bo;
    float cold = (t > 0) ? c_g[b * 256 + j] : 0.f;
    float cn = sigf(pf) * cold + sigf(pi) * tanhf(pg);
    float hn = sigf(po) * tanhf(cn);
    c_g[b * 256 + j] = cn;
    u16 hb = f2bf(hn);
    h_wr[b * 256 + j] = hb;
    out[((size_t)b * L + t_x) * 512 + dir * 256 + j] = hb;
  }
}

// ---------------------------------------------------------------------------
// Decoder attention 1 — scores from precomputed A_c (r1-proven numerics):
// scores_c[l] = A_c[b,l,:] · h. z-phase vectorized (r8).
// ---------------------------------------------------------------------------
__global__ __launch_bounds__(256) void attn1(
    const u16* A_c, const u16* insenc, u16* qattn, u16* qbuf) {
  int b = blockIdx.x, tid = threadIdx.x;
  __shared__ float su[512], red[256], aw[64];
  __shared__ float zacc[4][512];
  for (int d = tid; d < 512; d += 256) su[d] = bf2f(qbuf[(size_t)b * 1024 + d]);
  __syncthreads();
  {
    int l = tid >> 2, part = tid & 3;
    const u16* row = A_c + ((size_t)b * 64 + l) * 512 + part * 128;
    float s = 0.f;
    for (int k = 0; k < 128; k += 8) {
      bf16x8 v = load8(row + k);
#pragma unroll
      for (int e = 0; e < 8; e++) s += bf2f((u16)v[e]) * su[part * 128 + k + e];
    }
    red[tid] = s;
  }
  __syncthreads();
  if (tid < 64) {
    float sc = red[tid * 4] + red[tid * 4 + 1] + red[tid * 4 + 2] + red[tid * 4 + 3];
    float m = sc;
    for (int off = 32; off > 0; off >>= 1) m = fmaxf(m, __shfl_xor(m, off));
    float e = __expf(sc - m);
    float sm = e;
    for (int off = 32; off > 0; off >>= 1) sm += __shfl_xor(sm, off);
    aw[tid] = e / sm;
  }
  __syncthreads();
  {
    int part = tid >> 6, chunk = tid & 63;
    float a[8] = {};
    for (int l = part * 16; l < part * 16 + 16; l++) {
      bf16x8 v = load8(insenc + ((size_t)b * 64 + l) * 512 + chunk * 8);
      float w = aw[l];
#pragma unroll
      for (int e = 0; e < 8; e++) a[e] += w * bf2f((u16)v[e]);
    }
#pragma unroll
    for (int e = 0; e < 8; e++) zacc[part][chunk * 8 + e] = a[e];
  }
  __syncthreads();
  for (int d = tid; d < 512; d += 256) {
    float z = zacc[0][d] + zacc[1][d] + zacc[2][d] + zacc[3][d];
    u16 zb = f2bf(z);
    qattn[(size_t)b * 1024 + d] = zb;
    qbuf[(size_t)b * 1024 + 512 + d] = zb;
  }
}

// ---------------------------------------------------------------------------
// Decoder attention 2 (r8 verbatim — u_p f32 in, z-phase vectorized)
// ---------------------------------------------------------------------------
__global__ __launch_bounds__(256) void attn2(
    const float* u_p, const u16* hisenc, u16* qattn) {
  int b = blockIdx.x, tid = threadIdx.x;
  __shared__ float su[512], red[256], aw[128], mr[2];
  __shared__ float zacc[4][512];
  for (int d = tid; d < 512; d += 256) su[d] = u_p[b * 512 + d];
  __syncthreads();
  {
    int l = tid >> 1, part = tid & 1;
    const u16* row = hisenc + ((size_t)b * 128 + l) * 512 + part * 256;
    float s = 0.f;
    for (int k = 0; k < 256; k += 8) {
      bf16x8 v = load8(row + k);
#pragma unroll
      for (int e = 0; e < 8; e++) s += bf2f((u16)v[e]) * su[part * 256 + k + e];
    }
    red[tid] = s;
  }
  __syncthreads();
  float sc = (tid < 128) ? red[tid * 2] + red[tid * 2 + 1] : 0.f;
  __syncthreads();
  if (tid < 128) red[tid] = sc;
  __syncthreads();
  if (tid < 64) {
    float m = fmaxf(red[tid], red[tid + 64]);
    for (int off = 32; off > 0; off >>= 1) m = fmaxf(m, __shfl_xor(m, off));
    if (tid == 0) mr[0] = m;
  }
  __syncthreads();
  float ex = 0.f;
  if (tid < 128) { ex = __expf(sc - mr[0]); red[tid] = ex; }
  __syncthreads();
  if (tid < 64) {
    float s2 = red[tid] + red[tid + 64];
    for (int off = 32; off > 0; off >>= 1) s2 += __shfl_xor(s2, off);
    if (tid == 0) mr[1] = s2;
  }
  __syncthreads();
  if (tid < 128) aw[tid] = ex / mr[1];
  __syncthreads();
  {
    int part = tid >> 6, chunk = tid & 63;
    float a[8] = {};
    for (int l = part * 32; l < part * 32 + 32; l++) {
      bf16x8 v = load8(hisenc + ((size_t)b * 128 + l) * 512 + chunk * 8);
      float w = aw[l];
#pragma unroll
      for (int e = 0; e < 8; e++) a[e] += w * bf2f((u16)v[e]);
    }
#pragma unroll
    for (int e = 0; e < 8; e++) zacc[part][chunk * 8 + e] = a[e];
  }
  __syncthreads();
  for (int d = tid; d < 512; d += 256) {
    float z = zacc[0][d] + zacc[1][d] + zacc[2][d] + zacc[3][d];
    qattn[(size_t)b * 1024 + 512 + d] = f2bf(z);
  }
}

// decoder init (r0 verbatim)
__global__ void dec_init(const float* h0, const float* c0, u16* zin0, u16* qbuf, float* c_ws) {
  int idx = blockIdx.x * 256 + threadIdx.x; // 128*512
  int b = idx >> 9, d = idx & 511;
  u16 hv = f2bf(h0[idx]);
  zin0[(size_t)b * 1024 + 512 + d] = hv;
  qbuf[(size_t)b * 1024 + d] = hv;
  c_ws[idx] = c0[idx];
}

// ---------------------------------------------------------------------------
extern "C" void kernel_launch(void* const* d_in, const int* in_sizes, int n_in,
                              void* d_out, int out_size, void* d_ws, size_t ws_size,
                              hipStream_t stream) {
  const int* ins_tok = (const int*)d_in[0];
  const int* his_tok = (const int*)d_in[1];
  const int* actions = (const int*)d_in[2];
  const int* cur_env = (const int*)d_in[3];
  const int* ini_env = (const int*)d_in[4];
  const float* enc_emb = (const float*)d_in[5];
  const float* Wih_f = (const float*)d_in[6];
  const float* Whh_f = (const float*)d_in[7];
  const float* bih_f = (const float*)d_in[8];
  const float* bhh_f = (const float*)d_in[9];
  const float* Wih_b = (const float*)d_in[10];
  const float* Whh_b = (const float*)d_in[11];
  const float* bih_b = (const float*)d_in[12];
  const float* bhh_b = (const float*)d_in[13];
  const float* color_emb = (const float*)d_in[14];
  const float* pos_emb = (const float*)d_in[15];
  const float* ws_Wih = (const float*)d_in[16];
  const float* ws_Whh = (const float*)d_in[17];
  const float* ws_bih = (const float*)d_in[18];
  const float* ws_bhh = (const float*)d_in[19];
  const float* act_emb = (const float*)d_in[20];
  const float* W_c = (const float*)d_in[21];
  const float* W_p = (const float*)d_in[22];
  // d_in[23..26] are mathematically dead (uniform softmax over broadcast rows).
  const float* Wbd_W = (const float*)d_in[27];
  const float* Wbd_b = (const float*)d_in[28];
  const float* dec_Wih = (const float*)d_in[29];
  const float* dec_Whh = (const float*)d_in[30];
  const float* dec_bih = (const float*)d_in[31];
  const float* dec_bhh = (const float*)d_in[32];
  const float* h2a_W = (const float*)d_in[33];
  const float* h2a_b = (const float*)d_in[34];
  const float* h0 = (const float*)d_in[35];
  const float* c0 = (const float*)d_in[36];
  (void)in_sizes; (void)n_in; (void)out_size; (void)ws_size;

  char* ws = (char*)d_ws;
  size_t off = 0;
  auto alloc = [&](size_t bytes) -> char* {
    char* p = ws + off;
    off = (off + bytes + 255) & ~(size_t)255;
    return p;
  };
  u16* insenc   = (u16*)alloc(8192ull * 512 * 2);
  u16* hisenc   = (u16*)alloc(16384ull * 512 * 2);
  u16* outs     = (u16*)alloc(4096ull * 512 * 2);
  u16* Wsum     = (u16*)alloc(512ull * 896 * 2);
  u16* h_enc    = (u16*)alloc(2 * HBUF * 2);
  float* c_enc  = (float*)alloc(4ull * 128 * 256 * 4);
  float* projact= (float*)alloc(100ull * 512 * 4);
  float* bias_f = (float*)alloc(1024 * 4);
  float* bias_b = (float*)alloc(1024 * 4);
  float* bdecint= (float*)alloc(2048 * 4);
  float* bwbd   = (float*)alloc(512 * 4);
  float* bh2a   = (float*)alloc(128 * 4);
  u16* ctxcat   = (u16*)alloc(128ull * 896 * 2);
  float* hkbase = (float*)alloc(128ull * 512 * 4);
  float* u_p    = (float*)alloc(128ull * 512 * 4);
  u16* qbuf     = (u16*)alloc(128ull * 1024 * 2);     // [h | z_c]
  u16* qattn    = (u16*)alloc(128ull * 1024 * 2);     // [z_c | z_p]
  u16* zin      = (u16*)alloc(2ull * 128 * 1024 * 2); // [hk | h], parity
  float* c_dec  = (float*)alloc(128ull * 512 * 4);
  // x-projection tables: projE = enc_emb @ Wih^T per direction (f32)
  float* projE_f = (float*)alloc(2000ull * 1024 * 4); // 8.2 MB
  float* projE_b = (float*)alloc(2000ull * 1024 * 4); // 8.2 MB
  // A_c = insenc @ W_c (t-invariant attention projection, bf16, 8.4 MB)
  u16* A_c      = (u16*)alloc(8192ull * 512 * 2);
  // bf16 weight copies
  u16* emb_bf   = (u16*)alloc(2000ull * 128 * 2);
  u16* wihf_bf  = (u16*)alloc(1024ull * 128 * 2);
  u16* wihb_bf  = (u16*)alloc(1024ull * 128 * 2);
  u16* whhf_bf  = (u16*)alloc(1024ull * 256 * 2);
  u16* whhb_bf  = (u16*)alloc(1024ull * 256 * 2);
  u16* act_bf   = (u16*)alloc(100ull * 128 * 2);
  u16* wcT_bf   = (u16*)alloc(512ull * 512 * 2);      // W_c^T for A_c GEMM
  u16* wp_bf    = (u16*)alloc(512ull * 1024 * 2);
  u16* wbd01_bf = (u16*)alloc(512ull * 1024 * 2);
  u16* wbdx_bf  = (u16*)alloc(512ull * 128 * 2);
  u16* dwih_bf  = (u16*)alloc(2048ull * 512 * 2);
  u16* dwhh_bf  = (u16*)alloc(2048ull * 512 * 2);
  u16* h2a_bf   = (u16*)alloc(100ull * 512 * 2);

  // --- all weight conversions in ONE launch ---
  CvtJobs cj{};
  int nb = 0, jn = 0;
  auto addjob = [&](const float* s, u16* d, int R, int C, int ld, int c0c, int tr) {
    cj.j[jn] = { s, d, R, C, ld, c0c, tr, nb };
    nb += (R * C + 255) / 256;
    jn++;
  };
  addjob(enc_emb, emb_bf, 2000, 128, 128, 0, 0);
  addjob(Wih_f, wihf_bf, 1024, 128, 128, 0, 0);
  addjob(Wih_b, wihb_bf, 1024, 128, 128, 0, 0);
  addjob(Whh_f, whhf_bf, 1024, 256, 256, 0, 0);
  addjob(Whh_b, whhb_bf, 1024, 256, 256, 0, 0);
  addjob(act_emb, act_bf, 100, 128, 128, 0, 0);
  addjob(W_c, wcT_bf, 512, 512, 512, 0, 1);   // transposed: wcT[j][n] = W_c[n][j]
  addjob(W_p, wp_bf, 512, 1024, 1024, 0, 0);
  addjob(Wbd_W, wbd01_bf, 512, 1024, 2944, 0, 0);
  addjob(Wbd_W, wbdx_bf, 512, 128, 2944, 2816, 0);
  addjob(dec_Wih, dwih_bf, 2048, 512, 512, 0, 0);
  addjob(dec_Whh, dwhh_bf, 2048, 512, 512, 0, 0);
  addjob(h2a_W, h2a_bf, 100, 512, 512, 0, 0);
  cj.njobs = jn;
  cvt_all<<<nb, 256, 0, stream>>>(cj);

  // --- fused bias prep (was 5 kernels) ---
  prep_small<<<19, 256, 0, stream>>>(bih_f, bhh_f, bias_f, bih_b, bhh_b, bias_b,
                                     Wbd_b, bwbd, h2a_b, bh2a,
                                     dec_bih, dec_bhh, bdecint);
  wsum_build<<<1792, 256, 0, stream>>>(Wbd_W, Wsum);

  // --- projE tables: emb @ Wih^T per direction (M=2000, N=1024, K=128) ---
  {
    GemmArgs ge = {};
    ge.A = emb_bf; ge.lda = 128; ge.M = 2000; ge.W = wihf_bf; ge.ldw = 128;
    ge.N = 1024; ge.K = 128; ge.out = projE_f; ge.ldc = 1024;
    gemm_k<0><<<dim3(32, 16), 256, 0, stream>>>(ge);
    ge.W = wihb_bf; ge.out = projE_b;
    gemm_k<0><<<dim3(32, 16), 256, 0, stream>>>(ge);
  }

  // --- proj_act = act_emb @ Wbd_x^T + Wbd_b ---
  GemmArgs gp = {};
  gp.A = act_bf; gp.lda = 128; gp.M = 100; gp.W = wbdx_bf; gp.ldw = 128;
  gp.N = 512; gp.K = 128; gp.out = projact; gp.ldc = 512; gp.bias = bwbd;
  gemm_k<0><<<dim3(2, 8), 256, 0, stream>>>(gp);

  // --- env encode + hk_base ---
  env_encode<<<224, 256, 0, stream>>>(cur_env, ini_env, color_emb, pos_emb,
                                      ws_Wih, ws_Whh, ws_bih, ws_bhh, ctxcat);
  GemmArgs gb = {};
  gb.A = ctxcat; gb.lda = 896; gb.M = 128; gb.W = Wsum; gb.ldw = 896;
  gb.N = 512; gb.K = 896; gb.out = hkbase; gb.ldc = 512;
  gemm_k<0><<<dim3(2, 8), 256, 0, stream>>>(gb);

  // --- encoder: 128 sequential steps, 128-thread blocks (2x grid) ---
  for (int t = 0; t < 128; t++) {
    int cb = (t < 64) ? 0 : 2;
    int nbk = (t < 64) ? 256 : 128;
    enc_step3<<<nbk, 128, 0, stream>>>(t, cb, ins_tok, his_tok,
                                       projE_f, projE_b, whhf_bf, whhb_bf,
                                       bias_f, bias_b, h_enc, c_enc,
                                       insenc, hisenc);
  }

  // --- A_c = insenc @ W_c  (M=8192, N=512, K=512, bf16 out) ---
  {
    GemmArgs ga = {};
    ga.A = insenc; ga.lda = 512; ga.M = 8192; ga.W = wcT_bf; ga.ldw = 512;
    ga.N = 512; ga.K = 512; ga.out = A_c; ga.ldc = 512;
    gemm_k<1><<<dim3(128, 8), 256, 0, stream>>>(ga);
  }

  // --- decoder: 5 dispatches/step (attn1 -> u_p -> attn2 -> hk -> gates) ---
  dec_init<<<256, 256, 0, stream>>>(h0, c0, zin, qbuf, c_dec);
  for (int t = 0; t < 32; t++) {
    u16* zin_cur = zin + (size_t)(t & 1) * 128 * 1024;
    u16* zin_nxt = zin + (size_t)((t + 1) & 1) * 128 * 1024;
    // attn1: scores from A_c·h (u_c GEMM eliminated)
    attn1<<<128, 256, 0, stream>>>(A_c, insenc, qattn, qbuf);
    // u_p = W_p @ [h | z_c]  (K=1024) -> 64 blocks
    GemmArgs gv = {};
    gv.A = qbuf; gv.lda = 1024; gv.M = 128; gv.W = wp_bf; gv.ldw = 1024;
    gv.N = 512; gv.K = 1024; gv.out = u_p; gv.ldc = 512;
    gemm32_k<0><<<dim3(4, 16), 256, 0, stream>>>(gv);
    attn2<<<128, 256, 0, stream>>>(u_p, hisenc, qattn);
    // hk -> 64 blocks
    GemmArgs gh = {};
    gh.A = qattn; gh.lda = 1024; gh.M = 128; gh.W = wbd01_bf; gh.ldw = 1024;
    gh.N = 512; gh.K = 1024; gh.out = zin_cur; gh.ldc = 1024;
    gh.hk_base = hkbase; gh.proj_act = projact; gh.actions = actions; gh.t = t;
    gemm32_k<2><<<dim3(4, 16), 256, 0, stream>>>(gh);
    // gates + fused cell: 256 blocks
    dec_gates_cell32<<<dim3(4, 64), 256, 0, stream>>>(
        zin_cur, dwih_bf, dwhh_bf, bdecint, c_dec, zin_nxt, qbuf, outs, t);
  }

  // --- logits (f32 out): 32x32 tiles -> 512 blocks ---
  GemmArgs gl = {};
  gl.A = outs; gl.lda = 512; gl.M = 4096; gl.W = h2a_bf; gl.ldw = 512;
  gl.N = 100; gl.K = 512; gl.out = d_out; gl.ldc = 100; gl.bias = bh2a;
  gemm32_k<0><<<dim3(128, 4), 256, 0, stream>>>(gl);
}

// Round 10
// 2511.830 us; speedup vs baseline: 4.3336x; 1.0813x over previous
//
#include <hip/hip_runtime.h>

// Seq2Seq round 14 = r9 (2716us) + decoder phase-width cuts:
//  - attn1/attn2: 512 threads (score/z serial phases halved).
//  - u_p: K-split across 2x blocks (128 blks), partials summed in attn2.
//  - dec_init folded into prep_small (-1 dispatch).
// Encoder judged near structural floor (128 serial steps, L2-resident weights,
// 16-row MFMA reuse — finer decomposition breaks reuse, r1/r2/r3 evidence).

typedef unsigned short u16;
typedef __attribute__((ext_vector_type(8))) short bf16x8;
typedef __attribute__((ext_vector_type(4))) float f32x4;

#define DEVFN static __device__ __forceinline__

DEVFN float bf2f(u16 u) {
  unsigned int x = ((unsigned int)u) << 16;
  float f; __builtin_memcpy(&f, &x, 4); return f;
}
DEVFN u16 f2bf(float f) {
  unsigned int x; __builtin_memcpy(&x, &f, 4);
  x = (x + 0x7fffu + ((x >> 16) & 1u)) >> 16;
  return (u16)x;
}
DEVFN float sigf(float x) { return 1.f / (1.f + __expf(-x)); }
DEVFN bf16x8 load8(const u16* p) { return *(const bf16x8*)p; }
DEVFN int clampi(int v, int lo, int hi) { return v < lo ? lo : (v > hi ? hi : v); }

// ---------------------------------------------------------------------------
// Generic MFMA GEMM (64x64 block tile). EPI 0: f32 (+bias). EPI 1: bf16.
// ---------------------------------------------------------------------------
struct GemmArgs {
  const u16* A; int lda; int M;
  const u16* W; int ldw; int N; int K;
  void* out; int ldc;
  const float* bias;
  const float* hk_base; const float* proj_act; const int* actions; int t;
};

template <int EPI>
__global__ __launch_bounds__(256) void gemm_k(GemmArgs g) {
  int lane = threadIdx.x & 63;
  int wave = threadIdx.x >> 6;
  int col = lane & 15, q = lane >> 4;
  int m0 = blockIdx.x * 64 + (wave >> 1) * 32;
  int n0 = blockIdx.y * 64 + (wave & 1) * 32;
  f32x4 acc[2][2] = {};
  int rA[2] = { m0 + col, m0 + 16 + col };
  int rB[2] = { n0 + col, n0 + 16 + col };
  bool gA[2] = { rA[0] < g.M, rA[1] < g.M };
  bool gB[2] = { rB[0] < g.N, rB[1] < g.N };
  const u16* pA[2]; const u16* pB[2];
#pragma unroll
  for (int i = 0; i < 2; i++) {
    pA[i] = g.A + (size_t)(gA[i] ? rA[i] : 0) * g.lda + q * 8;
    pB[i] = g.W + (size_t)(gB[i] ? rB[i] : 0) * g.ldw + q * 8;
  }
  bf16x8 zf = {0,0,0,0,0,0,0,0};
  for (int k = 0; k < g.K; k += 32) {
    bf16x8 a0 = gA[0] ? load8(pA[0] + k) : zf;
    bf16x8 a1 = gA[1] ? load8(pA[1] + k) : zf;
    bf16x8 b0 = gB[0] ? load8(pB[0] + k) : zf;
    bf16x8 b1 = gB[1] ? load8(pB[1] + k) : zf;
    acc[0][0] = __builtin_amdgcn_mfma_f32_16x16x32_bf16(a0, b0, acc[0][0], 0, 0, 0);
    acc[0][1] = __builtin_amdgcn_mfma_f32_16x16x32_bf16(a0, b1, acc[0][1], 0, 0, 0);
    acc[1][0] = __builtin_amdgcn_mfma_f32_16x16x32_bf16(a1, b0, acc[1][0], 0, 0, 0);
    acc[1][1] = __builtin_amdgcn_mfma_f32_16x16x32_bf16(a1, b1, acc[1][1], 0, 0, 0);
  }
#pragma unroll
  for (int mi = 0; mi < 2; mi++)
#pragma unroll
    for (int ni = 0; ni < 2; ni++)
#pragma unroll
      for (int r = 0; r < 4; r++) {
        int m = m0 + mi * 16 + q * 4 + r;
        int n = n0 + ni * 16 + col;
        if (m >= g.M || n >= g.N) continue;
        float v = acc[mi][ni][r];
        if constexpr (EPI == 0) {
          if (g.bias) v += g.bias[n];
          ((float*)g.out)[(size_t)m * g.ldc + n] = v;
        } else {
          ((u16*)g.out)[(size_t)m * g.ldc + n] = f2bf(v);
        }
      }
}

// ---------------------------------------------------------------------------
// 32x32-block-tile MFMA GEMM (r7/r8 validated). EPI 0 / EPI 2 (hk).
// ---------------------------------------------------------------------------
template <int EPI>
__global__ __launch_bounds__(256) void gemm32_k(GemmArgs g) {
  int lane = threadIdx.x & 63;
  int wave = threadIdx.x >> 6;
  int col = lane & 15, q = lane >> 4;
  int m0 = blockIdx.x * 32 + (wave >> 1) * 16;
  int n0 = blockIdx.y * 32 + (wave & 1) * 16;
  f32x4 acc = {};
  int rA = m0 + col, rB = n0 + col;
  bool gA = rA < g.M, gB = rB < g.N;
  const u16* pA = g.A + (size_t)(gA ? rA : 0) * g.lda + q * 8;
  const u16* pB = g.W + (size_t)(gB ? rB : 0) * g.ldw + q * 8;
  bf16x8 zf = {0,0,0,0,0,0,0,0};
  for (int k = 0; k < g.K; k += 32) {
    bf16x8 a = gA ? load8(pA + k) : zf;
    bf16x8 b = gB ? load8(pB + k) : zf;
    acc = __builtin_amdgcn_mfma_f32_16x16x32_bf16(a, b, acc, 0, 0, 0);
  }
#pragma unroll
  for (int r = 0; r < 4; r++) {
    int m = m0 + q * 4 + r;
    int n = n0 + col;
    if (m >= g.M || n >= g.N) continue;
    float v = acc[r];
    if constexpr (EPI == 0) {
      if (g.bias) v += g.bias[n];
      ((float*)g.out)[(size_t)m * g.ldc + n] = v;
    } else {
      int act = clampi(g.actions[m * 32 + g.t], 0, 99);
      v += g.hk_base[m * 512 + n] + g.proj_act[(size_t)act * 512 + n];
      ((u16*)g.out)[(size_t)m * g.ldc + n] = f2bf(tanhf(v));
    }
  }
}

// ---------------------------------------------------------------------------
// u_p K-split: grid (4, 32). by<16 -> K-half 0; by>=16 -> K-half 1.
// out: u_p2[half][128][512] f32 partials (summed in attn2).
// ---------------------------------------------------------------------------
__global__ __launch_bounds__(256) void up_split(
    const u16* qbuf, const u16* wp, float* u_p2) {
  int lane = threadIdx.x & 63;
  int wave = threadIdx.x >> 6;
  int col = lane & 15, q = lane >> 4;
  int half = blockIdx.y >> 4;
  int by = blockIdx.y & 15;
  int m0 = blockIdx.x * 32 + (wave >> 1) * 16;
  int n0 = by * 32 + (wave & 1) * 16;
  f32x4 acc = {};
  const u16* pA = qbuf + (size_t)(m0 + col) * 1024 + half * 512 + q * 8;
  const u16* pB = wp + (size_t)(n0 + col) * 1024 + half * 512 + q * 8;
  for (int k = 0; k < 512; k += 32) {
    acc = __builtin_amdgcn_mfma_f32_16x16x32_bf16(load8(pA + k), load8(pB + k), acc, 0, 0, 0);
  }
  float* out = u_p2 + (size_t)half * 128 * 512;
#pragma unroll
  for (int r = 0; r < 4; r++) {
    int m = m0 + q * 4 + r;
    int n = n0 + col;
    out[(size_t)m * 512 + n] = acc[r];
  }
}

// ---------------------------------------------------------------------------
// Decoder gates GEMM + fused LSTM cell, 32x32 tiles (r8 verbatim).
// ---------------------------------------------------------------------------
__global__ __launch_bounds__(256) void dec_gates_cell32(
    const u16* zin_cur, const u16* Wih, const u16* Whh, const float* bias_int,
    float* c_ws, u16* zin_nxt, u16* qbuf, u16* outs, int t) {
  int lane = threadIdx.x & 63, wave = threadIdx.x >> 6;
  int col = lane & 15, q = lane >> 4;
  int m0 = blockIdx.x * 32 + (wave >> 1) * 16;
  int n0 = blockIdx.y * 32 + (wave & 1) * 16;
  f32x4 acc = {};
  const u16* pA = zin_cur + (size_t)(m0 + col) * 1024 + q * 8;
  int r = n0 + col;
  int src = (r & 3) * 512 + (r >> 2);
  const u16* pI = Wih + (size_t)src * 512 + q * 8;
  const u16* pH = Whh + (size_t)src * 512 + q * 8;
  for (int k = 0; k < 512; k += 32) {
    acc = __builtin_amdgcn_mfma_f32_16x16x32_bf16(load8(pA + k), load8(pI + k), acc, 0, 0, 0);
  }
  for (int k = 0; k < 512; k += 32) {
    acc = __builtin_amdgcn_mfma_f32_16x16x32_bf16(load8(pA + 512 + k), load8(pH + k), acc, 0, 0, 0);
  }
  __shared__ float ls[32][36];
#pragma unroll
  for (int rr = 0; rr < 4; rr++) {
    int ml = (wave >> 1) * 16 + q * 4 + rr;
    int nl = (wave & 1) * 16 + col;
    ls[ml][nl] = acc[rr] + bias_int[blockIdx.y * 32 + nl];
  }
  __syncthreads();
  int m = threadIdx.x & 31, jloc = threadIdx.x >> 5;
  int gm = blockIdx.x * 32 + m;
  int j = blockIdx.y * 8 + jloc;
  float gi = ls[m][jloc * 4 + 0];
  float gf = ls[m][jloc * 4 + 1];
  float gg = ls[m][jloc * 4 + 2];
  float go = ls[m][jloc * 4 + 3];
  float cn = sigf(gf) * c_ws[gm * 512 + j] + sigf(gi) * tanhf(gg);
  c_ws[gm * 512 + j] = cn;
  float hn = sigf(go) * tanhf(cn);
  u16 hb = f2bf(hn);
  zin_nxt[(size_t)gm * 1024 + 512 + j] = hb;
  qbuf[(size_t)gm * 1024 + j] = hb;
  outs[((size_t)gm * 32 + t) * 512 + j] = hb;
}

// ---------------------------------------------------------------------------
// prep kernels
// ---------------------------------------------------------------------------
struct CvtJob { const float* src; u16* dst; int R; int C; int ld; int c0; int tr; int blk0; };
struct CvtJobs { CvtJob j[15]; int njobs; };

__global__ void cvt_all(CvtJobs a) {
  int bid = blockIdx.x;
  int ji = 0;
  while (ji + 1 < a.njobs && bid >= a.j[ji + 1].blk0) ji++;
  CvtJob jb = a.j[ji];
  int idx = (bid - jb.blk0) * 256 + threadIdx.x;
  int n = jb.R * jb.C;
  if (idx >= n) return;
  int r = idx / jb.C, c = idx - r * jb.C;
  float v = jb.src[(size_t)r * jb.ld + jb.c0 + c];
  if (jb.tr) jb.dst[(size_t)c * jb.R + r] = f2bf(v);
  else jb.dst[idx] = f2bf(v);
}

// fused: bias_f | bias_b | bwbd | bh2a | bdecint | dec_init  (4708 + 65536)
__global__ void prep_small(
    const float* bih_f, const float* bhh_f, float* bias_f,
    const float* bih_b, const float* bhh_b, float* bias_b,
    const float* Wbd_b, float* bwbd,
    const float* h2a_b, float* bh2a,
    const float* dec_bih, const float* dec_bhh, float* bdecint,
    const float* h0, const float* c0, u16* zin0, u16* qbuf, float* c_ws) {
  int i = blockIdx.x * 256 + threadIdx.x;
  if (i < 1024) bias_f[i] = bih_f[i] + bhh_f[i];
  else if (i < 2048) { int k = i - 1024; bias_b[k] = bih_b[k] + bhh_b[k]; }
  else if (i < 2560) { int k = i - 2048; bwbd[k] = Wbd_b[k]; }
  else if (i < 2660) { int k = i - 2560; bh2a[k] = h2a_b[k]; }
  else if (i < 4708) {
    int r = i - 2660;
    int j = r >> 2, gg = r & 3;
    bdecint[r] = dec_bih[gg * 512 + j] + dec_bhh[gg * 512 + j];
  } else if (i < 4708 + 128 * 512) {
    int k = i - 4708;
    int b = k >> 9, d = k & 511;
    u16 hv = f2bf(h0[k]);
    zin0[(size_t)b * 1024 + 512 + d] = hv;
    qbuf[(size_t)b * 1024 + d] = hv;
    c_ws[k] = c0[k];
  }
}

__global__ void wsum_build(const float* Wbd, u16* Wsum) {
  int idx = blockIdx.x * 256 + threadIdx.x; // 512*896
  int n = idx / 896, j = idx % 896;
  int c1 = (j < 448) ? (1024 + j) : (1920 + (j - 448));
  int c2 = c1 + 448;
  Wsum[idx] = f2bf(Wbd[(size_t)n * 2944 + c1] + Wbd[(size_t)n * 2944 + c2]);
}

// ---------------------------------------------------------------------------
// Env encoder (r0 verbatim)
// ---------------------------------------------------------------------------
__global__ __launch_bounds__(256) void env_encode(
    const int* cur_env, const int* ini_env,
    const float* color_emb, const float* pos_emb,
    const float* wih, const float* whh, const float* bih, const float* bhh,
    u16* ctx_cat) {
  __shared__ float s_wih[128 * 33], s_whh[128 * 33], s_b[128], s_col[7 * 32];
  __shared__ float h_lds[8][33];
  int tid = threadIdx.x;
  for (int i = tid; i < 128 * 32; i += 256) {
    int r = i >> 5, k2 = i & 31;
    s_wih[r * 33 + k2] = wih[i];
    s_whh[r * 33 + k2] = whh[i];
  }
  for (int i = tid; i < 128; i += 256) s_b[i] = bih[i] + bhh[i];
  for (int i = tid; i < 224; i += 256) s_col[i] = color_emb[i];
  int sl = tid >> 5, j = tid & 31;
  int gseq = blockIdx.x * 8 + sl;
  int e = gseq / 896, rem = gseq % 896;
  int b = rem / 7, p = rem % 7;
  const int* env = e ? ini_env : cur_env;
  int eoff = e ? 0 : 448;
  h_lds[sl][j] = 0.f;
  __syncthreads();
  float cj = 0.f, hj = 0.f;
  for (int st = 0; st < 4; st++) {
    int tok = clampi(env[b * 35 + p * 5 + 1 + st], 0, 6);
    const float* x = &s_col[tok * 32];
    float pi = s_b[j], pf = s_b[32 + j], pg = s_b[64 + j], po = s_b[96 + j];
    for (int k = 0; k < 32; k++) {
      float xk = x[k], hk = h_lds[sl][k];
      pi += s_wih[j * 33 + k] * xk + s_whh[j * 33 + k] * hk;
      pf += s_wih[(32 + j) * 33 + k] * xk + s_whh[(32 + j) * 33 + k] * hk;
      pg += s_wih[(64 + j) * 33 + k] * xk + s_whh[(64 + j) * 33 + k] * hk;
      po += s_wih[(96 + j) * 33 + k] * xk + s_whh[(96 + j) * 33 + k] * hk;
    }
    cj = sigf(pf) * cj + sigf(pi) * tanhf(pg);
    hj = sigf(po) * tanhf(cj);
    __syncthreads();
    h_lds[sl][j] = hj;
    __syncthreads();
  }
  size_t base = (size_t)b * 896 + eoff + p * 64;
  ctx_cat[base + j] = f2bf(pos_emb[p * 32 + j]);
  ctx_cat[base + 32 + j] = f2bf(hj);
}

// ---------------------------------------------------------------------------
// Encoder step v3 (r9 verbatim): 128-thread blocks.
// ---------------------------------------------------------------------------
#define HBUF ((size_t)4 * 128 * 256)
__global__ __launch_bounds__(128) void enc_step3(
    int t, int chainbase,
    const int* ins_tok, const int* his_tok,
    const float* projE_f, const float* projE_b,
    const u16* whh_f, const u16* whh_b,
    const float* bias_f, const float* bias_b,
    u16* h_enc, float* c_enc,
    u16* ins_enc, u16* his_enc) {
  int chain = chainbase + (blockIdx.x >> 6);
  int sub = blockIdx.x & 63;
  int sgrp = sub >> 3, jq = sub & 7;
  int w = threadIdx.x >> 6, lane = threadIdx.x & 63;
  int col = lane & 15, q = lane >> 4;
  int dir = chain & 1, his = chain >> 1;
  int L = his ? 128 : 64;
  const int* toks = his ? his_tok : ins_tok;
  int t_x = dir ? (L - 1 - t) : t;
  const float* projE = dir ? projE_b : projE_f;
  const u16* whh = dir ? whh_b : whh_f;
  const float* bias = dir ? bias_b : bias_f;
  const u16* h_rd = h_enc + ((size_t)((t & 1) ^ 1)) * HBUF + (size_t)chain * 128 * 256;
  u16* h_wr = h_enc + ((size_t)(t & 1)) * HBUF + (size_t)chain * 128 * 256;
  float* c_g = c_enc + (size_t)chain * 128 * 256;
  u16* out = his ? his_enc : ins_enc;

  int jw = jq * 32 + w * 16;
  f32x4 acc[4] = {};
  if (t > 0) {
    const u16* hrow = h_rd + (size_t)(sgrp * 16 + col) * 256 + q * 8;
    const u16* wrow[4];
#pragma unroll
    for (int G = 0; G < 4; G++) wrow[G] = whh + (size_t)(G * 256 + jw + col) * 256 + q * 8;
    for (int k = 0; k < 256; k += 32) {
      bf16x8 a = load8(hrow + k);
#pragma unroll
      for (int G = 0; G < 4; G++) {
        bf16x8 bb = load8(wrow[G] + k);
        acc[G] = __builtin_amdgcn_mfma_f32_16x16x32_bf16(a, bb, acc[G], 0, 0, 0);
      }
    }
  }
  int j = jw + col;
  float bi = bias[j], bf = bias[256 + j], bg = bias[512 + j], bo = bias[768 + j];
#pragma unroll
  for (int r = 0; r < 4; r++) {
    int s = q * 4 + r;
    int b = sgrp * 16 + s;
    int tok = clampi(toks[b * L + t_x], 0, 1999);
    const float* px = projE + (size_t)tok * 1024;
    float pi = acc[0][r] + px[j] + bi;
    float pf = acc[1][r] + px[256 + j] + bf;
    float pg = acc[2][r] + px[512 + j] + bg;
    float po = acc[3][r] + px[768 + j] + bo;
    float cold = (t > 0) ? c_g[b * 256 + j] : 0.f;
    float cn = sigf(pf) * cold + sigf(pi) * tanhf(pg);
    float hn = sigf(po) * tanhf(cn);
    c_g[b * 256 + j] = cn;
    u16 hb = f2bf(hn);
    h_wr[b * 256 + j] = hb;
    out[((size_t)b * L + t_x) * 512 + dir * 256 + j] = hb;
  }
}

// ---------------------------------------------------------------------------
// Decoder attention 1 — 512 threads. Scores from A_c·h; z vectorized 8-way.
// ---------------------------------------------------------------------------
__global__ __launch_bounds__(512) void attn1(
    const u16* A_c, const u16* insenc, u16* qattn, u16* qbuf) {
  int b = blockIdx.x, tid = threadIdx.x;
  __shared__ float su[512], red[512], aw[64];
  __shared__ float zacc[8][512];
  su[tid] = bf2f(qbuf[(size_t)b * 1024 + tid]);
  __syncthreads();
  // scores: l = tid>>3 (64 l's), part = tid&7 (64 cols each)
  {
    int l = tid >> 3, part = tid & 7;
    const u16* row = A_c + ((size_t)b * 64 + l) * 512 + part * 64;
    float s = 0.f;
    for (int k = 0; k < 64; k += 8) {
      bf16x8 v = load8(row + k);
#pragma unroll
      for (int e = 0; e < 8; e++) s += bf2f((u16)v[e]) * su[part * 64 + k + e];
    }
    red[tid] = s;
  }
  __syncthreads();
  if (tid < 64) {
    float sc = 0.f;
#pragma unroll
    for (int i = 0; i < 8; i++) sc += red[tid * 8 + i];
    float m = sc;
    for (int off = 32; off > 0; off >>= 1) m = fmaxf(m, __shfl_xor(m, off));
    float e = __expf(sc - m);
    float sm = e;
    for (int off = 32; off > 0; off >>= 1) sm += __shfl_xor(sm, off);
    aw[tid] = e / sm;
  }
  __syncthreads();
  // z: part = tid>>6 (8 parts x 8 l), chunk = tid&63 (8 d's vector)
  {
    int part = tid >> 6, chunk = tid & 63;
    float a[8] = {};
    for (int l = part * 8; l < part * 8 + 8; l++) {
      bf16x8 v = load8(insenc + ((size_t)b * 64 + l) * 512 + chunk * 8);
      float w = aw[l];
#pragma unroll
      for (int e = 0; e < 8; e++) a[e] += w * bf2f((u16)v[e]);
    }
#pragma unroll
    for (int e = 0; e < 8; e++) zacc[part][chunk * 8 + e] = a[e];
  }
  __syncthreads();
  {
    float z = zacc[0][tid] + zacc[1][tid] + zacc[2][tid] + zacc[3][tid]
            + zacc[4][tid] + zacc[5][tid] + zacc[6][tid] + zacc[7][tid];
    u16 zb = f2bf(z);
    qattn[(size_t)b * 1024 + tid] = zb;
    qbuf[(size_t)b * 1024 + 512 + tid] = zb;
  }
}

// ---------------------------------------------------------------------------
// Decoder attention 2 — 512 threads; u_p from 2 K-split partials.
// ---------------------------------------------------------------------------
__global__ __launch_bounds__(512) void attn2(
    const float* u_p2, const u16* hisenc, u16* qattn) {
  int b = blockIdx.x, tid = threadIdx.x;
  __shared__ float su[512], red[512], aw[128], mr[2];
  __shared__ float zacc[8][512];
  su[tid] = u_p2[(size_t)b * 512 + tid] + u_p2[65536 + (size_t)b * 512 + tid];
  __syncthreads();
  // scores: l = tid>>2 (128 l's), part = tid&3 (128 cols each)
  {
    int l = tid >> 2, part = tid & 3;
    const u16* row = hisenc + ((size_t)b * 128 + l) * 512 + part * 128;
    float s = 0.f;
    for (int k = 0; k < 128; k += 8) {
      bf16x8 v = load8(row + k);
#pragma unroll
      for (int e = 0; e < 8; e++) s += bf2f((u16)v[e]) * su[part * 128 + k + e];
    }
    red[tid] = s;
  }
  __syncthreads();
  float sc = 0.f;
  if (tid < 128) sc = red[tid * 4] + red[tid * 4 + 1] + red[tid * 4 + 2] + red[tid * 4 + 3];
  __syncthreads();
  if (tid < 128) red[tid] = sc;
  __syncthreads();
  if (tid < 64) {
    float m = fmaxf(red[tid], red[tid + 64]);
    for (int off = 32; off > 0; off >>= 1) m = fmaxf(m, __shfl_xor(m, off));
    if (tid == 0) mr[0] = m;
  }
  __syncthreads();
  float ex = 0.f;
  if (tid < 128) { ex = __expf(sc - mr[0]); red[tid] = ex; }
  __syncthreads();
  if (tid < 64) {
    float s2 = red[tid] + red[tid + 64];
    for (int off = 32; off > 0; off >>= 1) s2 += __shfl_xor(s2, off);
    if (tid == 0) mr[1] = s2;
  }
  __syncthreads();
  if (tid < 128) aw[tid] = ex / mr[1];
  __syncthreads();
  // z: part = tid>>6 (8 parts x 16 l), chunk = tid&63
  {
    int part = tid >> 6, chunk = tid & 63;
    float a[8] = {};
    for (int l = part * 16; l < part * 16 + 16; l++) {
      bf16x8 v = load8(hisenc + ((size_t)b * 128 + l) * 512 + chunk * 8);
      float w = aw[l];
#pragma unroll
      for (int e = 0; e < 8; e++) a[e] += w * bf2f((u16)v[e]);
    }
#pragma unroll
    for (int e = 0; e < 8; e++) zacc[part][chunk * 8 + e] = a[e];
  }
  __syncthreads();
  {
    float z = zacc[0][tid] + zacc[1][tid] + zacc[2][tid] + zacc[3][tid]
            + zacc[4][tid] + zacc[5][tid] + zacc[6][tid] + zacc[7][tid];
    qattn[(size_t)b * 1024 + 512 + tid] = f2bf(z);
  }
}

// ---------------------------------------------------------------------------
extern "C" void kernel_launch(void* const* d_in, const int* in_sizes, int n_in,
                              void* d_out, int out_size, void* d_ws, size_t ws_size,
                              hipStream_t stream) {
  const int* ins_tok = (const int*)d_in[0];
  const int* his_tok = (const int*)d_in[1];
  const int* actions = (const int*)d_in[2];
  const int* cur_env = (const int*)d_in[3];
  const int* ini_env = (const int*)d_in[4];
  const float* enc_emb = (const float*)d_in[5];
  const float* Wih_f = (const float*)d_in[6];
  const float* Whh_f = (const float*)d_in[7];
  const float* bih_f = (const float*)d_in[8];
  const float* bhh_f = (const float*)d_in[9];
  const float* Wih_b = (const float*)d_in[10];
  const float* Whh_b = (const float*)d_in[11];
  const float* bih_b = (const float*)d_in[12];
  const float* bhh_b = (const float*)d_in[13];
  const float* color_emb = (const float*)d_in[14];
  const float* pos_emb = (const float*)d_in[15];
  const float* ws_Wih = (const float*)d_in[16];
  const float* ws_Whh = (const float*)d_in[17];
  const float* ws_bih = (const float*)d_in[18];
  const float* ws_bhh = (const float*)d_in[19];
  const float* act_emb = (const float*)d_in[20];
  const float* W_c = (const float*)d_in[21];
  const float* W_p = (const float*)d_in[22];
  // d_in[23..26] are mathematically dead (uniform softmax over broadcast rows).
  const float* Wbd_W = (const float*)d_in[27];
  const float* Wbd_b = (const float*)d_in[28];
  const float* dec_Wih = (const float*)d_in[29];
  const float* dec_Whh = (const float*)d_in[30];
  const float* dec_bih = (const float*)d_in[31];
  const float* dec_bhh = (const float*)d_in[32];
  const float* h2a_W = (const float*)d_in[33];
  const float* h2a_b = (const float*)d_in[34];
  const float* h0 = (const float*)d_in[35];
  const float* c0 = (const float*)d_in[36];
  (void)in_sizes; (void)n_in; (void)out_size; (void)ws_size;

  char* ws = (char*)d_ws;
  size_t off = 0;
  auto alloc = [&](size_t bytes) -> char* {
    char* p = ws + off;
    off = (off + bytes + 255) & ~(size_t)255;
    return p;
  };
  u16* insenc   = (u16*)alloc(8192ull * 512 * 2);
  u16* hisenc   = (u16*)alloc(16384ull * 512 * 2);
  u16* outs     = (u16*)alloc(4096ull * 512 * 2);
  u16* Wsum     = (u16*)alloc(512ull * 896 * 2);
  u16* h_enc    = (u16*)alloc(2 * HBUF * 2);
  float* c_enc  = (float*)alloc(4ull * 128 * 256 * 4);
  float* projact= (float*)alloc(100ull * 512 * 4);
  float* bias_f = (float*)alloc(1024 * 4);
  float* bias_b = (float*)alloc(1024 * 4);
  float* bdecint= (float*)alloc(2048 * 4);
  float* bwbd   = (float*)alloc(512 * 4);
  float* bh2a   = (float*)alloc(128 * 4);
  u16* ctxcat   = (u16*)alloc(128ull * 896 * 2);
  float* hkbase = (float*)alloc(128ull * 512 * 4);
  float* u_p2   = (float*)alloc(2ull * 128 * 512 * 4);  // K-split partials
  u16* qbuf     = (u16*)alloc(128ull * 1024 * 2);     // [h | z_c]
  u16* qattn    = (u16*)alloc(128ull * 1024 * 2);     // [z_c | z_p]
  u16* zin      = (u16*)alloc(2ull * 128 * 1024 * 2); // [hk | h], parity
  float* c_dec  = (float*)alloc(128ull * 512 * 4);
  float* projE_f = (float*)alloc(2000ull * 1024 * 4);
  float* projE_b = (float*)alloc(2000ull * 1024 * 4);
  u16* A_c      = (u16*)alloc(8192ull * 512 * 2);
  // bf16 weight copies
  u16* emb_bf   = (u16*)alloc(2000ull * 128 * 2);
  u16* wihf_bf  = (u16*)alloc(1024ull * 128 * 2);
  u16* wihb_bf  = (u16*)alloc(1024ull * 128 * 2);
  u16* whhf_bf  = (u16*)alloc(1024ull * 256 * 2);
  u16* whhb_bf  = (u16*)alloc(1024ull * 256 * 2);
  u16* act_bf   = (u16*)alloc(100ull * 128 * 2);
  u16* wcT_bf   = (u16*)alloc(512ull * 512 * 2);
  u16* wp_bf    = (u16*)alloc(512ull * 1024 * 2);
  u16* wbd01_bf = (u16*)alloc(512ull * 1024 * 2);
  u16* wbdx_bf  = (u16*)alloc(512ull * 128 * 2);
  u16* dwih_bf  = (u16*)alloc(2048ull * 512 * 2);
  u16* dwhh_bf  = (u16*)alloc(2048ull * 512 * 2);
  u16* h2a_bf   = (u16*)alloc(100ull * 512 * 2);

  // --- all weight conversions in ONE launch ---
  CvtJobs cj{};
  int nb = 0, jn = 0;
  auto addjob = [&](const float* s, u16* d, int R, int C, int ld, int c0c, int tr) {
    cj.j[jn] = { s, d, R, C, ld, c0c, tr, nb };
    nb += (R * C + 255) / 256;
    jn++;
  };
  addjob(enc_emb, emb_bf, 2000, 128, 128, 0, 0);
  addjob(Wih_f, wihf_bf, 1024, 128, 128, 0, 0);
  addjob(Wih_b, wihb_bf, 1024, 128, 128, 0, 0);
  addjob(Whh_f, whhf_bf, 1024, 256, 256, 0, 0);
  addjob(Whh_b, whhb_bf, 1024, 256, 256, 0, 0);
  addjob(act_emb, act_bf, 100, 128, 128, 0, 0);
  addjob(W_c, wcT_bf, 512, 512, 512, 0, 1);   // transposed
  addjob(W_p, wp_bf, 512, 1024, 1024, 0, 0);
  addjob(Wbd_W, wbd01_bf, 512, 1024, 2944, 0, 0);
  addjob(Wbd_W, wbdx_bf, 512, 128, 2944, 2816, 0);
  addjob(dec_Wih, dwih_bf, 2048, 512, 512, 0, 0);
  addjob(dec_Whh, dwhh_bf, 2048, 512, 512, 0, 0);
  addjob(h2a_W, h2a_bf, 100, 512, 512, 0, 0);
  cj.njobs = jn;
  cvt_all<<<nb, 256, 0, stream>>>(cj);

  // --- fused bias prep + dec_init ---
  prep_small<<<(4708 + 128 * 512 + 255) / 256, 256, 0, stream>>>(
      bih_f, bhh_f, bias_f, bih_b, bhh_b, bias_b,
      Wbd_b, bwbd, h2a_b, bh2a, dec_bih, dec_bhh, bdecint,
      h0, c0, zin, qbuf, c_dec);
  wsum_build<<<1792, 256, 0, stream>>>(Wbd_W, Wsum);

  // --- projE tables ---
  {
    GemmArgs ge = {};
    ge.A = emb_bf; ge.lda = 128; ge.M = 2000; ge.W = wihf_bf; ge.ldw = 128;
    ge.N = 1024; ge.K = 128; ge.out = projE_f; ge.ldc = 1024;
    gemm_k<0><<<dim3(32, 16), 256, 0, stream>>>(ge);
    ge.W = wihb_bf; ge.out = projE_b;
    gemm_k<0><<<dim3(32, 16), 256, 0, stream>>>(ge);
  }

  // --- proj_act = act_emb @ Wbd_x^T + Wbd_b ---
  GemmArgs gp = {};
  gp.A = act_bf; gp.lda = 128; gp.M = 100; gp.W = wbdx_bf; gp.ldw = 128;
  gp.N = 512; gp.K = 128; gp.out = projact; gp.ldc = 512; gp.bias = bwbd;
  gemm_k<0><<<dim3(2, 8), 256, 0, stream>>>(gp);

  // --- env encode + hk_base ---
  env_encode<<<224, 256, 0, stream>>>(cur_env, ini_env, color_emb, pos_emb,
                                      ws_Wih, ws_Whh, ws_bih, ws_bhh, ctxcat);
  GemmArgs gb = {};
  gb.A = ctxcat; gb.lda = 896; gb.M = 128; gb.W = Wsum; gb.ldw = 896;
  gb.N = 512; gb.K = 896; gb.out = hkbase; gb.ldc = 512;
  gemm_k<0><<<dim3(2, 8), 256, 0, stream>>>(gb);

  // --- encoder: 128 sequential steps, 128-thread blocks ---
  for (int t = 0; t < 128; t++) {
    int cb = (t < 64) ? 0 : 2;
    int nbk = (t < 64) ? 256 : 128;
    enc_step3<<<nbk, 128, 0, stream>>>(t, cb, ins_tok, his_tok,
                                       projE_f, projE_b, whhf_bf, whhb_bf,
                                       bias_f, bias_b, h_enc, c_enc,
                                       insenc, hisenc);
  }

  // --- A_c = insenc @ W_c ---
  {
    GemmArgs ga = {};
    ga.A = insenc; ga.lda = 512; ga.M = 8192; ga.W = wcT_bf; ga.ldw = 512;
    ga.N = 512; ga.K = 512; ga.out = A_c; ga.ldc = 512;
    gemm_k<1><<<dim3(128, 8), 256, 0, stream>>>(ga);
  }

  // --- decoder: 5 dispatches/step ---
  for (int t = 0; t < 32; t++) {
    u16* zin_cur = zin + (size_t)(t & 1) * 128 * 1024;
    u16* zin_nxt = zin + (size_t)((t + 1) & 1) * 128 * 1024;
    attn1<<<128, 512, 0, stream>>>(A_c, insenc, qattn, qbuf);
    // u_p K-split: 128 blocks (2 K-halves x 64)
    up_split<<<dim3(4, 32), 256, 0, stream>>>(qbuf, wp_bf, u_p2);
    attn2<<<128, 512, 0, stream>>>(u_p2, hisenc, qattn);
    // hk -> 64 blocks
    GemmArgs gh = {};
    gh.A = qattn; gh.lda = 1024; gh.M = 128; gh.W = wbd01_bf; gh.ldw = 1024;
    gh.N = 512; gh.K = 1024; gh.out = zin_cur; gh.ldc = 1024;
    gh.hk_base = hkbase; gh.proj_act = projact; gh.actions = actions; gh.t = t;
    gemm32_k<2><<<dim3(4, 16), 256, 0, stream>>>(gh);
    // gates + fused cell: 256 blocks
    dec_gates_cell32<<<dim3(4, 64), 256, 0, stream>>>(
        zin_cur, dwih_bf, dwhh_bf, bdecint, c_dec, zin_nxt, qbuf, outs, t);
  }

  // --- logits (f32 out): 512 blocks ---
  GemmArgs gl = {};
  gl.A = outs; gl.lda = 512; gl.M = 4096; gl.W = h2a_bf; gl.ldw = 512;
  gl.N = 100; gl.K = 512; gl.out = d_out; gl.ldc = 100; gl.bias = bh2a;
  gemm32_k<0><<<dim3(128, 4), 256, 0, stream>>>(gl);
}